// Round 6
// baseline (939.424 us; speedup 1.0000x reference)
//
#include <hip/hip_runtime.h>
#include <math.h>

#define PI_D 3.14159265358979323846

#define BSZ   512
#define NODE  66
#define VL    35
#define DCTN  20

static constexpr float BN_INVS = 0.99999500003749969f; // 1/sqrt(1+1e-5)

typedef unsigned short u16;
typedef unsigned int   u32;
using bf16x8 = __attribute__((ext_vector_type(8))) short;
using f32x4  = __attribute__((ext_vector_type(4))) float;

#define AS1 __attribute__((address_space(1)))
#define AS3 __attribute__((address_space(3)))

__device__ __forceinline__ void gl16(const u16* g, u16* l) {
    // async global->LDS DMA, 16B per lane; LDS dest = wave-uniform base + lane*16
    __builtin_amdgcn_global_load_lds((const AS1 u32*)g, (AS3 u32*)l, 16, 0, 0);
}

__device__ inline u16 f2bf(float f) {
    union { float f; u32 u; } v; v.f = f;
    u32 r = v.u + 0x7FFFu + ((v.u >> 16) & 1u);
    return (u16)(r >> 16);
}
__device__ inline float bf2f(u16 b) {
    union { u32 u; float f; } v; v.u = ((u32)b) << 16;
    return v.f;
}

// ---------------- dct20 (20 x 35), orthonormal DCT-II rows ----------------
__global__ void dct_kernel(float* __restrict__ dct20) {
    int i = blockIdx.x * blockDim.x + threadIdx.x;
    if (i < DCTN * VL) {
        int k = i / VL, v = i - k * VL;
        double w = (k == 0) ? sqrt(1.0 / VL) : sqrt(2.0 / VL);
        dct20[i] = (float)(w * cos(PI_D * (v + 0.5) * k / (double)VL));
    }
}

// ---------------- weight conversion / transpose to bf16 ----------------
__global__ void cvt_gcb(const float* __restrict__ W, u16* __restrict__ Wt) {
    int l = blockIdx.y;
    int i = blockIdx.x * 256 + threadIdx.x;
    int n = i >> 9, k = i & 511;
    Wt[(size_t)l * 262144 + i] = f2bf(W[(size_t)l * 262144 + (size_t)k * 512 + n]);
}
__global__ void cvt_gc1(const float* __restrict__ W, u16* __restrict__ Wt) {
    int i = blockIdx.x * 256 + threadIdx.x;
    int n = i >> 6, k = i & 63;
    Wt[i] = (k < 40) ? f2bf(W[k * 512 + n]) : (u16)0;
}
__global__ void cvt_gc7(const float* __restrict__ W, u16* __restrict__ Wt) {
    int i = blockIdx.x * 256 + threadIdx.x;
    int n = i >> 9, k = i & 511;
    Wt[i] = (n < 20) ? f2bf(W[k * 40 + n]) : (u16)0;
}
__global__ void cvt_w1(const float* __restrict__ W, u16* __restrict__ Wt) {
    int i = blockIdx.x * 256 + threadIdx.x;
    int d = i / 416, k = i - d * 416;
    float v = 0.f;
    if (k < 396) { int h = k / 66, c = k - h * 66; v = W[d * 396 + c * 6 + h]; }
    Wt[i] = f2bf(v);
}
__global__ void cvt_w2(const float* __restrict__ W, u16* __restrict__ Wt) {
    int i = blockIdx.x * 256 + threadIdx.x;
    int d = i / 2560, k = i - d * 2560;
    int h = k >> 9, c = k & 511;
    Wt[i] = f2bf(W[(size_t)d * 2560 + c * 5 + h]);
}
// A matrices (66x66) -> prepadded bf16 [6][80][104] (cols 66..103 zero)
__global__ void cvt_att(const float* __restrict__ gc1A, const float* __restrict__ gcbA,
                        const float* __restrict__ gc7A, u16* __restrict__ Abf) {
    int l = blockIdx.y;
    int i = blockIdx.x * 256 + threadIdx.x;
    if (i < 8320) {
        int r = i / 104, c = i - (i / 104) * 104;
        float v = 0.f;
        if (r < 66 && c < 66) {
            const float* A = (l == 0) ? gc1A : (l <= 4 ? gcbA + (size_t)(l - 1) * 4356 : gc7A);
            v = A[r * 66 + c];
        }
        Abf[(size_t)l * 8320 + i] = f2bf(v);
    }
}

// ---------------- fused GCN layer: y' = epi( A_g @ (Y @ W) ) ----------------
// Block = 2 batches (132 rows staged as 144) x 128 f-cols, 4 waves.
// LDS (39.25KB): K-loop uses AsF[4][144][8] + BsF[4][128][8] plane-major tiles,
// staged via global_load_lds(16B); after the loop the SAME memory is reused as
// zT[f][152] (t^T in bf16; b0 at cols 0..65, b1 at 72..137; pads+tail zeroed so
// A's zero-pad never multiplies NaN). Phase 2: A(80x96pad) @ zT via MFMA.
// EPI: 2 = bn+tanh -> bf16 y ; 3 = bn+tanh+res -> bf16 y ; 4 = +bias+x -> fp32 dctout
template<int EPI>
__global__ __launch_bounds__(256, 4) void gc_fused(const u16* __restrict__ Y,
                                                   const u16* __restrict__ Wt,
                                                   const u16* __restrict__ Ab,
                                                   void* __restrict__ Yout, int K,
                                                   const float* __restrict__ bias,
                                                   const float* __restrict__ g,
                                                   const float* __restrict__ be,
                                                   const u16* __restrict__ yres,
                                                   const float* __restrict__ xres) {
    __shared__ u16 smem[19624];          // 39.25 KB
    u16* AsF = smem;                     // [4][144][8] = 4608 u16
    u16* BsF = smem + 4608;              // [4][128][8] = 4096 u16
    u16* zT  = smem;                     // [129][152]+tail, aliases AsF/BsF

    const int tid = threadIdx.x;
    const int b0 = blockIdx.x * 2;
    const int n0 = blockIdx.y * 128;
    const int lane = tid & 63, w = tid >> 6;
    const int row16 = lane & 15, grp = lane >> 4;

    int k0;
    auto stageA = [&](int c) {   // 1KB call c of AsF flat [0,9216)B
        int flat = c * 1024 + lane * 16;
        int plane = flat / 2304;                 // 144*16B per plane
        int row = (flat - plane * 2304) >> 4;
        long grow = (long)b0 * 66 + row; if (grow > 33791) grow = 33791;
        gl16(Y + (size_t)grow * K + k0 + plane * 8, AsF + c * 512);
    };
    auto stageB = [&](int c) {
        int row = ((c & 1) << 6) + lane;
        gl16(Wt + (size_t)(n0 + row) * K + k0 + (c >> 1) * 8, BsF + c * 512);
    };

    f32x4 acc[9][2] = {};
    for (k0 = 0; k0 < K; k0 += 32) {
        stageA(w); stageA(w + 4); if (w == 0) stageA(8);
        stageB(2 * w); stageB(2 * w + 1);
        __syncthreads();
        const int aoff = grp * 1152 + row16 * 8;
        const int boff = grp * 1024 + (w * 32 + row16) * 8;
        bf16x8 b[2];
#pragma unroll
        for (int nt = 0; nt < 2; ++nt) b[nt] = *(const bf16x8*)&BsF[boff + nt * 128];
#pragma unroll
        for (int mc = 0; mc < 3; ++mc) {     // 3 chunks of 3 m-tiles (VGPR cap)
            bf16x8 a[3];
#pragma unroll
            for (int i = 0; i < 3; ++i) a[i] = *(const bf16x8*)&AsF[aoff + (mc * 3 + i) * 128];
#pragma unroll
            for (int i = 0; i < 3; ++i)
#pragma unroll
                for (int nt = 0; nt < 2; ++nt)
                    acc[mc * 3 + i][nt] = __builtin_amdgcn_mfma_f32_16x16x32_bf16(a[i], b[nt], acc[mc * 3 + i][nt], 0, 0, 0);
        }
        __syncthreads();
    }

    // zero zT pads: cols 66..71 & 138..151 (rows 0..127) + tail [19456,19624)
    for (int i = tid; i < 128 * 20; i += 256) {
        int f = i / 20, j = i - (i / 20) * 20;
        int c = (j < 6) ? (66 + j) : (132 + j);   // j>=6 -> 138..151
        zT[f * 152 + c] = 0;
    }
    for (int i = tid; i < 168; i += 256) zT[19456 + i] = 0;

    // pack t^T into zT (b1 shifted +6 -> base col 72)
#pragma unroll
    for (int mt = 0; mt < 9; ++mt) {
        int m = mt * 16 + grp * 4;
        if (m < 132) {
#pragma unroll
            for (int nt = 0; nt < 2; ++nt) {
                int f = w * 32 + nt * 16 + row16;
                u16 e0 = f2bf(acc[mt][nt][0]), e1 = f2bf(acc[mt][nt][1]);
                u16 e2 = f2bf(acc[mt][nt][2]), e3 = f2bf(acc[mt][nt][3]);
                if (m + 3 < 66 || m >= 66) {
                    int col = (m < 66) ? m : m + 6;
                    *(u32*)&zT[f * 152 + col]     = (u32)e0 | ((u32)e1 << 16);
                    *(u32*)&zT[f * 152 + col + 2] = (u32)e2 | ((u32)e3 << 16);
                } else { // m=64 straddle: 64,65 | 72,73
                    zT[f * 152 + 64] = e0; zT[f * 152 + 65] = e1;
                    zT[f * 152 + 72] = e2; zT[f * 152 + 73] = e3;
                }
            }
        }
    }

    // A fragments from global (L2-hot)
    bf16x8 aA[5][3];
#pragma unroll
    for (int mt = 0; mt < 5; ++mt)
#pragma unroll
        for (int k2 = 0; k2 < 3; ++k2)
            aA[mt][k2] = *(const bf16x8*)&Ab[(mt * 16 + row16) * 104 + k2 * 32 + grp * 8];
    __syncthreads();

    f32x4 acc2[2][5][2] = {};
#pragma unroll
    for (int bb = 0; bb < 2; ++bb) {
        const int base = bb * 72;
#pragma unroll
        for (int k2 = 0; k2 < 3; ++k2) {
            bf16x8 bz[2];
#pragma unroll
            for (int ft = 0; ft < 2; ++ft)
                bz[ft] = *(const bf16x8*)&zT[(w * 32 + ft * 16 + row16) * 152 + base + k2 * 32 + grp * 8];
#pragma unroll
            for (int mt = 0; mt < 5; ++mt)
#pragma unroll
                for (int ft = 0; ft < 2; ++ft)
                    acc2[bb][mt][ft] = __builtin_amdgcn_mfma_f32_16x16x32_bf16(aA[mt][k2], bz[ft], acc2[bb][mt][ft], 0, 0, 0);
        }
    }

    // epilogue
#pragma unroll
    for (int bb = 0; bb < 2; ++bb) {
        const int bidx = b0 + bb;
#pragma unroll
        for (int mt = 0; mt < 5; ++mt) {
            int nb = mt * 16 + grp * 4;
#pragma unroll
            for (int ft = 0; ft < 2; ++ft) {
                int c = n0 + w * 32 + ft * 16 + row16;
#pragma unroll
                for (int j = 0; j < 4; ++j) {
                    int n = nb + j;
                    if (n < 66) {
                        float v = acc2[bb][mt][ft][j];
                        if constexpr (EPI == 4) {
                            if (c < 20)
                                ((float*)Yout)[(size_t)bidx * 1320 + n * 20 + c] =
                                    v + bias[c] + xres[(size_t)bidx * 2640 + n * 40 + c];
                        } else {
                            int gi = n * 512 + c;
                            float z = v + bias[c];
                            float t = tanhf(z * (g[gi] * BN_INVS) + be[gi]);
                            if constexpr (EPI == 3) t += bf2f(yres[((size_t)bidx * 66 + n) * 512 + c]);
                            ((u16*)Yout)[((size_t)bidx * 66 + n) * 512 + c] = f2bf(t);
                        }
                    }
                }
            }
        }
    }
}

// ---------------- unified bf16 MFMA GEMM (conv stacks) ----------------
// Plane-major LDS [4][128][8]; bf16 paths staged via global_load_lds(16B).
// ASRC: 1 = bf16 conv window (in[b][TIN][512], k-contig);
//       2 = fp32 src window (src[b][50][66], k<396 guard, *1e-3) - manual stage
// EPI:  0 = relu -> bf16 (ldc); 1 = relu -> fp32 (ldc)
template<int ASRC, int EPI, int TOUT, int TIN, int T0>
__global__ __launch_bounds__(256) void gemm_uni(const void* __restrict__ Asrc,
                                                const u16* __restrict__ Bt,
                                                void* __restrict__ Cout,
                                                int M, int K, int Nvalid, int ldc) {
    __shared__ u16 AsF[4096];   // [4][128][8]
    __shared__ u16 BsF[4096];
    const int tid = threadIdx.x;
    const int r0 = blockIdx.x * 128, n0 = blockIdx.y * 128;
    const int lane = tid & 63, w = tid >> 6;
    const int wr = (w >> 1) * 64, wc = (w & 1) * 64;
    const int row16 = lane & 15, grp = lane >> 4;
    const int sr = tid >> 1, sq = (tid & 1) * 16;

    const float* apf = nullptr;
    if constexpr (ASRC == 2) {
        int R = r0 + sr; int b = R / TOUT, t = R - b * TOUT;
        apf = (const float*)Asrc + (size_t)b * 3300 + (T0 + t) * 66 + sq;
    }

    f32x4 acc[4][4] = {};
    for (int k0 = 0; k0 < K; k0 += 32) {
        if constexpr (ASRC == 1) {
#pragma unroll
            for (int i = 0; i < 2; ++i) {
                int c = 2 * w + i;
                int row = ((c & 1) << 6) + lane;
                int R = r0 + row; int b = R / TOUT, t = R - b * TOUT;
                gl16((const u16*)Asrc + ((size_t)b * TIN + t) * 512 + k0 + (c >> 1) * 8,
                     AsF + c * 512);
            }
        } else {
#pragma unroll
            for (int j = 0; j < 16; ++j) {
                int k = k0 + sq + j;
                float vin = 0.f;
                if (k < 396) vin = apf[k0 + j];
                int col = sq + j;
                AsF[(col >> 3) * 1024 + sr * 8 + (col & 7)] = f2bf(vin * 1e-3f);
            }
        }
#pragma unroll
        for (int i = 0; i < 2; ++i) {
            int c = 2 * w + i;
            int row = ((c & 1) << 6) + lane;
            gl16(Bt + (size_t)(n0 + row) * K + k0 + (c >> 1) * 8, BsF + c * 512);
        }
        __syncthreads();
        bf16x8 a[4], b[4];
#pragma unroll
        for (int m = 0; m < 4; ++m) a[m] = *(const bf16x8*)&AsF[grp * 1024 + (wr + m * 16 + row16) * 8];
#pragma unroll
        for (int n = 0; n < 4; ++n) b[n] = *(const bf16x8*)&BsF[grp * 1024 + (wc + n * 16 + row16) * 8];
#pragma unroll
        for (int m = 0; m < 4; ++m)
#pragma unroll
            for (int n = 0; n < 4; ++n)
                acc[m][n] = __builtin_amdgcn_mfma_f32_16x16x32_bf16(a[m], b[n], acc[m][n], 0, 0, 0);
        __syncthreads();
    }
#pragma unroll
    for (int m = 0; m < 4; ++m) {
        int rb = r0 + wr + m * 16 + grp * 4;
#pragma unroll
        for (int n = 0; n < 4; ++n) {
            int c = n0 + wc + n * 16 + row16;
            if (c < Nvalid) {
#pragma unroll
                for (int j = 0; j < 4; ++j) {
                    float v = fmaxf(acc[m][n][j], 0.f);
                    if constexpr (EPI == 0) ((u16*)Cout)[(size_t)(rb + j) * ldc + c] = f2bf(v);
                    else                    ((float*)Cout)[(size_t)(rb + j) * ldc + c] = v;
                }
            }
        }
    }
}

// ---------------- attention weights: att[b,n] ----------------
__global__ __launch_bounds__(256) void att_kernel(const float* __restrict__ qT,
                                                  const float* __restrict__ kT,
                                                  float* __restrict__ att) {
    const int b = blockIdx.x, tid = threadIdx.x;
    __shared__ float part[256];
    __shared__ float sc[16];
    int n = tid >> 4, j = tid & 15;
    const float* q = qT + b * 512;
    const float* k = kT + b * 8192 + n * 512;
    float acc = 0.f;
    for (int d = j; d < 512; d += 16) acc += q[d] * k[d];
    part[tid] = acc;
    __syncthreads();
    if (tid < 16) {
        float s = 0.f;
        for (int jj = 0; jj < 16; ++jj) s += part[tid * 16 + jj];
        sc[tid] = s + 1e-15f;
    }
    __syncthreads();
    if (tid == 0) {
        float tot = 0.f;
        for (int nn = 0; nn < 16; ++nn) tot += sc[nn];
        float inv = 1.f / tot;
        for (int nn = 0; nn < 16; ++nn) att[b * 16 + nn] = sc[nn] * inv;
    }
}

// ---------------- build x : fp32 (b,66,40) + bf16 padded (b,66,64) ------------
__global__ __launch_bounds__(256) void xbuild(const float* __restrict__ src,
                                              const float* __restrict__ att,
                                              const float* __restrict__ dct20,
                                              float* __restrict__ x,
                                              u16* __restrict__ xbf) {
    const int b = blockIdx.x, tid = threadIdx.x;
    __shared__ float s_src[50 * 66];
    __shared__ float s_sacc[VL * 66];
    __shared__ float s_d[DCTN * VL];
    __shared__ float s_att[16];
    for (int i = tid; i < 3300; i += 256) s_src[i] = src[b * 3300 + i];
    for (int i = tid; i < DCTN * VL; i += 256) s_d[i] = dct20[i];
    if (tid < 16) s_att[tid] = att[b * 16 + tid];
    __syncthreads();
    for (int i = tid; i < VL * 66; i += 256) {
        int v = i / 66, f = i - (i / 66) * 66;
        float a = 0.f;
#pragma unroll
        for (int n = 0; n < 16; ++n) a += s_att[n] * s_src[(n + v) * 66 + f];
        s_sacc[i] = a;
    }
    __syncthreads();
    for (int i = tid; i < 66 * DCTN; i += 256) {
        int f = i / DCTN, kq = i - (i / DCTN) * DCTN;
        float din = 0.f, datt = 0.f;
        for (int v = 0; v < VL; ++v) {
            float dv = s_d[kq * VL + v];
            int t2 = (v < 10) ? (40 + v) : 49;
            din += dv * s_src[t2 * 66 + f];
            datt += dv * s_sacc[v * 66 + f];
        }
        x[b * 2640 + f * 40 + kq] = din;
        x[b * 2640 + f * 40 + 20 + kq] = datt;
        xbf[(size_t)b * 4224 + f * 64 + kq] = f2bf(din);
        xbf[(size_t)b * 4224 + f * 64 + 20 + kq] = f2bf(datt);
    }
    for (int i = tid; i < 66 * 24; i += 256) {
        int f = i / 24, kp = 40 + (i - (i / 24) * 24);
        xbf[(size_t)b * 4224 + f * 64 + kp] = 0;
    }
}

// ---------------- out[b,v,f] = sum_k dct20[k,v]*dctout[b,f,k] ----------------
__global__ __launch_bounds__(256) void final_out(const float* __restrict__ dctout,
                                                 const float* __restrict__ dct20,
                                                 float* __restrict__ out) {
    const int b = blockIdx.x, tid = threadIdx.x;
    __shared__ float ds[DCTN * VL];
    __shared__ float dos[66 * 20];
    for (int i = tid; i < DCTN * VL; i += 256) ds[i] = dct20[i];
    for (int i = tid; i < 1320; i += 256) dos[i] = dctout[(size_t)b * 1320 + i];
    __syncthreads();
    for (int o = tid; o < VL * 66; o += 256) {
        int v = o / 66, f = o - (o / 66) * 66;
        float acc = 0.f;
#pragma unroll
        for (int k = 0; k < DCTN; ++k) acc += ds[k * VL + v] * dos[f * 20 + k];
        out[(size_t)b * 2310 + o] = acc;
    }
}

extern "C" void kernel_launch(void* const* d_in, const int* in_sizes, int n_in,
                              void* d_out, int out_size, void* d_ws, size_t ws_size,
                              hipStream_t stream) {
    const float* src     = (const float*)d_in[0];
    const float* Wq1     = (const float*)d_in[1];
    const float* Wq2     = (const float*)d_in[2];
    const float* Wk1     = (const float*)d_in[3];
    const float* Wk2     = (const float*)d_in[4];
    const float* gc1_W   = (const float*)d_in[5];
    const float* gc1_att = (const float*)d_in[6];
    const float* gc1_b   = (const float*)d_in[7];
    const float* bn1_g   = (const float*)d_in[8];
    const float* bn1_b   = (const float*)d_in[9];
    const float* gcb_W   = (const float*)d_in[10];
    const float* gcb_att = (const float*)d_in[11];
    const float* gcb_b   = (const float*)d_in[12];
    const float* gcb_g   = (const float*)d_in[13];
    const float* gcb_be  = (const float*)d_in[14];
    const float* gc7_W   = (const float*)d_in[15];
    const float* gc7_att = (const float*)d_in[16];
    const float* gc7_b   = (const float*)d_in[17];
    float* out = (float*)d_out;

    unsigned char* base = (unsigned char*)d_ws;
    size_t off = 0;
    auto take = [&](size_t bytes) -> void* {
        void* p = base + off;
        off += (bytes + 255) & ~(size_t)255;
        return p;
    };
    u16*   yA     = (u16*)take((size_t)33792 * 512 * 2);
    u16*   yB     = (u16*)take((size_t)33792 * 512 * 2);
    float* xb     = (float*)take((size_t)512 * 2640 * 4);
    u16*   xbf    = (u16*)take((size_t)512 * 4224 * 2);
    float* dct20  = (float*)take(2800);
    float* dctout = (float*)take((size_t)512 * 1320 * 4);
    u16*   key1   = (u16*)take((size_t)512 * 20 * 512 * 2);
    u16*   q1     = (u16*)take((size_t)512 * 5 * 512 * 2);
    float* keyT   = (float*)take((size_t)8192 * 512 * 4);
    float* queryT = (float*)take((size_t)512 * 512 * 4);
    float* attw   = (float*)take((size_t)512 * 16 * 4);
    u16*   WtGcb  = (u16*)take((size_t)4 * 512 * 512 * 2);
    u16*   WtGc1  = (u16*)take((size_t)512 * 64 * 2);
    u16*   WtGc7  = (u16*)take((size_t)128 * 512 * 2);
    u16*   WtW1k  = (u16*)take((size_t)512 * 416 * 2);
    u16*   WtW1q  = (u16*)take((size_t)512 * 416 * 2);
    u16*   WtW2k  = (u16*)take((size_t)512 * 2560 * 2);
    u16*   WtW2q  = (u16*)take((size_t)512 * 2560 * 2);
    u16*   Abf    = (u16*)take((size_t)6 * 8320 * 2);

    dct_kernel<<<2, 384, 0, stream>>>(dct20);
    cvt_att<<<dim3(33, 6), 256, 0, stream>>>(gc1_att, gcb_att, gc7_att, Abf);
    cvt_gcb<<<dim3(1024, 4), 256, 0, stream>>>(gcb_W, WtGcb);
    cvt_gc1<<<128, 256, 0, stream>>>(gc1_W, WtGc1);
    cvt_gc7<<<256, 256, 0, stream>>>(gc7_W, WtGc7);
    cvt_w1<<<832, 256, 0, stream>>>(Wk1, WtW1k);
    cvt_w1<<<832, 256, 0, stream>>>(Wq1, WtW1q);
    cvt_w2<<<5120, 256, 0, stream>>>(Wk2, WtW2k);
    cvt_w2<<<5120, 256, 0, stream>>>(Wq2, WtW2q);

    // conv stacks (im2col is a strided view -> read inputs directly)
    gemm_uni<2, 0, 20, 25, 0><<<dim3(80, 4), 256, 0, stream>>>(
        src, WtW1k, key1, 10240, 416, 512, 512);
    gemm_uni<2, 0, 5, 10, 40><<<dim3(20, 4), 256, 0, stream>>>(
        src, WtW1q, q1, 2560, 416, 512, 512);
    gemm_uni<1, 1, 16, 20, 0><<<dim3(64, 4), 256, 0, stream>>>(
        key1, WtW2k, keyT, 8192, 2560, 512, 512);
    gemm_uni<1, 1, 1, 5, 0><<<dim3(4, 4), 256, 0, stream>>>(
        q1, WtW2q, queryT, 512, 2560, 512, 512);
    att_kernel<<<BSZ, 256, 0, stream>>>(queryT, keyT, attw);
    xbuild<<<BSZ, 256, 0, stream>>>(src, attw, dct20, xb, xbf);

    // gc1: yA = tanh(bn(A1 @ (x @ W1) + b))
    gc_fused<2><<<dim3(256, 4), 256, 0, stream>>>(
        xbf, WtGc1, Abf, yA, 64, gc1_b, bn1_g, bn1_b, nullptr, nullptr);

    // stages
    for (int st = 0; st < 2; ++st) {
        const u16* W0 = WtGcb + (size_t)(st * 2 + 0) * 262144;
        const u16* W1 = WtGcb + (size_t)(st * 2 + 1) * 262144;
        const u16* A0 = Abf + (size_t)(1 + st * 2) * 8320;
        const u16* A1 = Abf + (size_t)(2 + st * 2) * 8320;
        const float* b0  = gcb_b + (size_t)(st * 2 + 0) * 512;
        const float* b1  = gcb_b + (size_t)(st * 2 + 1) * 512;
        const float* g0  = gcb_g + (size_t)(st * 2 + 0) * 33792;
        const float* g1  = gcb_g + (size_t)(st * 2 + 1) * 33792;
        const float* be0 = gcb_be + (size_t)(st * 2 + 0) * 33792;
        const float* be1 = gcb_be + (size_t)(st * 2 + 1) * 33792;
        gc_fused<2><<<dim3(256, 4), 256, 0, stream>>>(
            yA, W0, A0, yB, 512, b0, g0, be0, nullptr, nullptr);
        gc_fused<3><<<dim3(256, 4), 256, 0, stream>>>(
            yB, W1, A1, yA, 512, b1, g1, be1, yA, nullptr);
    }

    // gc7: dctout = A7 @ (y @ W7) + b7 + x  (first 20 cols)
    gc_fused<4><<<dim3(256, 1), 256, 0, stream>>>(
        yA, WtGc7, Abf + (size_t)5 * 8320, dctout, 512, gc7_b, nullptr, nullptr, nullptr, xb);
    final_out<<<BSZ, 256, 0, stream>>>(dctout, dct20, out);
}

// Round 7
// 830.711 us; speedup vs baseline: 1.1309x; 1.1309x over previous
//
#include <hip/hip_runtime.h>
#include <math.h>

#define PI_D 3.14159265358979323846

#define BSZ   512
#define NODE  66
#define VL    35
#define DCTN  20

static constexpr float BN_INVS = 0.99999500003749969f; // 1/sqrt(1+1e-5)

typedef unsigned short u16;
typedef unsigned int   u32;
using bf16x8 = __attribute__((ext_vector_type(8))) short;
using f32x4  = __attribute__((ext_vector_type(4))) float;

#define AS1 __attribute__((address_space(1)))
#define AS3 __attribute__((address_space(3)))

__device__ __forceinline__ void gl16(const u16* g, u16* l) {
    // async global->LDS DMA, 16B per lane; LDS dest = wave-uniform base + lane*16
    __builtin_amdgcn_global_load_lds((const AS1 u32*)g, (AS3 u32*)l, 16, 0, 0);
}

__device__ inline u16 f2bf(float f) {
    union { float f; u32 u; } v; v.f = f;
    u32 r = v.u + 0x7FFFu + ((v.u >> 16) & 1u);
    return (u16)(r >> 16);
}
__device__ inline float bf2f(u16 b) {
    union { u32 u; float f; } v; v.u = ((u32)b) << 16;
    return v.f;
}

// ---------------- dct20 (20 x 35), orthonormal DCT-II rows ----------------
__global__ void dct_kernel(float* __restrict__ dct20) {
    int i = blockIdx.x * blockDim.x + threadIdx.x;
    if (i < DCTN * VL) {
        int k = i / VL, v = i - k * VL;
        double w = (k == 0) ? sqrt(1.0 / VL) : sqrt(2.0 / VL);
        dct20[i] = (float)(w * cos(PI_D * (v + 0.5) * k / (double)VL));
    }
}

// ---------------- weight conversion / transpose to bf16 ----------------
__global__ void cvt_gcb(const float* __restrict__ W, u16* __restrict__ Wt) {
    int l = blockIdx.y;
    int i = blockIdx.x * 256 + threadIdx.x;
    int n = i >> 9, k = i & 511;
    Wt[(size_t)l * 262144 + i] = f2bf(W[(size_t)l * 262144 + (size_t)k * 512 + n]);
}
__global__ void cvt_gc1(const float* __restrict__ W, u16* __restrict__ Wt) {
    int i = blockIdx.x * 256 + threadIdx.x;
    int n = i >> 6, k = i & 63;
    Wt[i] = (k < 40) ? f2bf(W[k * 512 + n]) : (u16)0;
}
__global__ void cvt_gc7(const float* __restrict__ W, u16* __restrict__ Wt) {
    int i = blockIdx.x * 256 + threadIdx.x;
    int n = i >> 9, k = i & 511;
    Wt[i] = (n < 20) ? f2bf(W[k * 40 + n]) : (u16)0;
}
__global__ void cvt_w1(const float* __restrict__ W, u16* __restrict__ Wt) {
    int i = blockIdx.x * 256 + threadIdx.x;
    int d = i / 416, k = i - d * 416;
    float v = 0.f;
    if (k < 396) { int h = k / 66, c = k - h * 66; v = W[d * 396 + c * 6 + h]; }
    Wt[i] = f2bf(v);
}
__global__ void cvt_w2(const float* __restrict__ W, u16* __restrict__ Wt) {
    int i = blockIdx.x * 256 + threadIdx.x;
    int d = i / 2560, k = i - d * 2560;
    int h = k >> 9, c = k & 511;
    Wt[i] = f2bf(W[(size_t)d * 2560 + c * 5 + h]);
}
// A matrices (66x66) -> prepadded bf16 [6][80][104] (cols 66..103 zero)
__global__ void cvt_att(const float* __restrict__ gc1A, const float* __restrict__ gcbA,
                        const float* __restrict__ gc7A, u16* __restrict__ Abf) {
    int l = blockIdx.y;
    int i = blockIdx.x * 256 + threadIdx.x;
    if (i < 8320) {
        int r = i / 104, c = i - (i / 104) * 104;
        float v = 0.f;
        if (r < 66 && c < 66) {
            const float* A = (l == 0) ? gc1A : (l <= 4 ? gcbA + (size_t)(l - 1) * 4356 : gc7A);
            v = A[r * 66 + c];
        }
        Abf[(size_t)l * 8320 + i] = f2bf(v);
    }
}

// ---------------- fused GCN layer: y' = epi( A_g @ (Y @ W) ) ----------------
// Block = 2 batches (132 rows staged as 144) x 128 f-cols, 4 waves.
// LDS (39.25KB): K-loop uses AsF[4][144][8] + BsF[4][128][8] plane-major tiles,
// staged via global_load_lds(16B); after the loop the SAME memory is reused as
// zT[f][152]. NOTE: no min-wave launch bound — R6's (256,4) forced VGPR=64 and
// spilled acc to scratch (+100MB HBM/dispatch). Compiler picks ~116-128 here,
// which still yields 4 blocks/CU with 39.25KB LDS.
// EPI: 2 = bn+tanh -> bf16 y ; 3 = bn+tanh+res -> bf16 y ; 4 = +bias+x -> fp32 dctout
template<int EPI>
__global__ __launch_bounds__(256) void gc_fused(const u16* __restrict__ Y,
                                                const u16* __restrict__ Wt,
                                                const u16* __restrict__ Ab,
                                                void* __restrict__ Yout, int K,
                                                const float* __restrict__ bias,
                                                const float* __restrict__ g,
                                                const float* __restrict__ be,
                                                const u16* __restrict__ yres,
                                                const float* __restrict__ xres) {
    __shared__ u16 smem[19624];          // 39.25 KB
    u16* AsF = smem;                     // [4][144][8] = 4608 u16
    u16* BsF = smem + 4608;              // [4][128][8] = 4096 u16
    u16* zT  = smem;                     // [129][152]+tail, aliases AsF/BsF

    const int tid = threadIdx.x;
    const int b0 = blockIdx.x * 2;
    const int n0 = blockIdx.y * 128;
    const int lane = tid & 63, w = tid >> 6;
    const int row16 = lane & 15, grp = lane >> 4;

    int k0;
    auto stageA = [&](int c) {   // 1KB call c of AsF flat [0,9216)B
        int flat = c * 1024 + lane * 16;
        int plane = flat / 2304;                 // 144*16B per plane
        int row = (flat - plane * 2304) >> 4;
        long grow = (long)b0 * 66 + row; if (grow > 33791) grow = 33791;
        gl16(Y + (size_t)grow * K + k0 + plane * 8, AsF + c * 512);
    };
    auto stageB = [&](int c) {
        int row = ((c & 1) << 6) + lane;
        gl16(Wt + (size_t)(n0 + row) * K + k0 + (c >> 1) * 8, BsF + c * 512);
    };

    f32x4 acc[9][2] = {};
    for (k0 = 0; k0 < K; k0 += 32) {
        stageA(w); stageA(w + 4); if (w == 0) stageA(8);
        stageB(2 * w); stageB(2 * w + 1);
        __syncthreads();
        const int aoff = grp * 1152 + row16 * 8;
        const int boff = grp * 1024 + (w * 32 + row16) * 8;
        bf16x8 b[2];
#pragma unroll
        for (int nt = 0; nt < 2; ++nt) b[nt] = *(const bf16x8*)&BsF[boff + nt * 128];
#pragma unroll
        for (int mc = 0; mc < 3; ++mc) {     // 3 chunks of 3 m-tiles
            bf16x8 a[3];
#pragma unroll
            for (int i = 0; i < 3; ++i) a[i] = *(const bf16x8*)&AsF[aoff + (mc * 3 + i) * 128];
#pragma unroll
            for (int i = 0; i < 3; ++i)
#pragma unroll
                for (int nt = 0; nt < 2; ++nt)
                    acc[mc * 3 + i][nt] = __builtin_amdgcn_mfma_f32_16x16x32_bf16(a[i], b[nt], acc[mc * 3 + i][nt], 0, 0, 0);
        }
        __syncthreads();
    }

    // zero zT pads: cols 66..71 & 138..151 (rows 0..127) + tail [19456,19624)
    for (int i = tid; i < 128 * 20; i += 256) {
        int f = i / 20, j = i - (i / 20) * 20;
        int c = (j < 6) ? (66 + j) : (132 + j);   // j>=6 -> 138..151
        zT[f * 152 + c] = 0;
    }
    for (int i = tid; i < 168; i += 256) zT[19456 + i] = 0;

    // pack t^T into zT (b1 shifted +6 -> base col 72)
#pragma unroll
    for (int mt = 0; mt < 9; ++mt) {
        int m = mt * 16 + grp * 4;
        if (m < 132) {
#pragma unroll
            for (int nt = 0; nt < 2; ++nt) {
                int f = w * 32 + nt * 16 + row16;
                u16 e0 = f2bf(acc[mt][nt][0]), e1 = f2bf(acc[mt][nt][1]);
                u16 e2 = f2bf(acc[mt][nt][2]), e3 = f2bf(acc[mt][nt][3]);
                if (m + 3 < 66 || m >= 66) {
                    int col = (m < 66) ? m : m + 6;
                    *(u32*)&zT[f * 152 + col]     = (u32)e0 | ((u32)e1 << 16);
                    *(u32*)&zT[f * 152 + col + 2] = (u32)e2 | ((u32)e3 << 16);
                } else { // m=64 straddle: 64,65 | 72,73
                    zT[f * 152 + 64] = e0; zT[f * 152 + 65] = e1;
                    zT[f * 152 + 72] = e2; zT[f * 152 + 73] = e3;
                }
            }
        }
    }

    // A fragments from global (L2-hot)
    bf16x8 aA[5][3];
#pragma unroll
    for (int mt = 0; mt < 5; ++mt)
#pragma unroll
        for (int k2 = 0; k2 < 3; ++k2)
            aA[mt][k2] = *(const bf16x8*)&Ab[(mt * 16 + row16) * 104 + k2 * 32 + grp * 8];
    __syncthreads();

    f32x4 acc2[2][5][2] = {};
#pragma unroll
    for (int bb = 0; bb < 2; ++bb) {
        const int base = bb * 72;
#pragma unroll
        for (int k2 = 0; k2 < 3; ++k2) {
            bf16x8 bz[2];
#pragma unroll
            for (int ft = 0; ft < 2; ++ft)
                bz[ft] = *(const bf16x8*)&zT[(w * 32 + ft * 16 + row16) * 152 + base + k2 * 32 + grp * 8];
#pragma unroll
            for (int mt = 0; mt < 5; ++mt)
#pragma unroll
                for (int ft = 0; ft < 2; ++ft)
                    acc2[bb][mt][ft] = __builtin_amdgcn_mfma_f32_16x16x32_bf16(aA[mt][k2], bz[ft], acc2[bb][mt][ft], 0, 0, 0);
        }
    }

    // epilogue
#pragma unroll
    for (int bb = 0; bb < 2; ++bb) {
        const int bidx = b0 + bb;
#pragma unroll
        for (int mt = 0; mt < 5; ++mt) {
            int nb = mt * 16 + grp * 4;
#pragma unroll
            for (int ft = 0; ft < 2; ++ft) {
                int c = n0 + w * 32 + ft * 16 + row16;
#pragma unroll
                for (int j = 0; j < 4; ++j) {
                    int n = nb + j;
                    if (n < 66) {
                        float v = acc2[bb][mt][ft][j];
                        if constexpr (EPI == 4) {
                            if (c < 20)
                                ((float*)Yout)[(size_t)bidx * 1320 + n * 20 + c] =
                                    v + bias[c] + xres[(size_t)bidx * 2640 + n * 40 + c];
                        } else {
                            int gi = n * 512 + c;
                            float z = v + bias[c];
                            float t = tanhf(z * (g[gi] * BN_INVS) + be[gi]);
                            if constexpr (EPI == 3) t += bf2f(yres[((size_t)bidx * 66 + n) * 512 + c]);
                            ((u16*)Yout)[((size_t)bidx * 66 + n) * 512 + c] = f2bf(t);
                        }
                    }
                }
            }
        }
    }
}

// ---------------- unified bf16 MFMA GEMM (conv stacks) ----------------
// Plane-major LDS [4][128][8]; bf16 paths staged via global_load_lds(16B).
// ASRC: 1 = bf16 conv window (in[b][TIN][512], k-contig);
//       2 = fp32 src window (src[b][50][66], k<396 guard, *1e-3) - manual stage
// EPI:  0 = relu -> bf16 (ldc); 1 = relu -> fp32 (ldc)
template<int ASRC, int EPI, int TOUT, int TIN, int T0>
__global__ __launch_bounds__(256) void gemm_uni(const void* __restrict__ Asrc,
                                                const u16* __restrict__ Bt,
                                                void* __restrict__ Cout,
                                                int M, int K, int Nvalid, int ldc) {
    __shared__ u16 AsF[4096];   // [4][128][8]
    __shared__ u16 BsF[4096];
    const int tid = threadIdx.x;
    const int r0 = blockIdx.x * 128, n0 = blockIdx.y * 128;
    const int lane = tid & 63, w = tid >> 6;
    const int wr = (w >> 1) * 64, wc = (w & 1) * 64;
    const int row16 = lane & 15, grp = lane >> 4;
    const int sr = tid >> 1, sq = (tid & 1) * 16;

    const float* apf = nullptr;
    if constexpr (ASRC == 2) {
        int R = r0 + sr; int b = R / TOUT, t = R - b * TOUT;
        apf = (const float*)Asrc + (size_t)b * 3300 + (T0 + t) * 66 + sq;
    }

    f32x4 acc[4][4] = {};
    for (int k0 = 0; k0 < K; k0 += 32) {
        if constexpr (ASRC == 1) {
#pragma unroll
            for (int i = 0; i < 2; ++i) {
                int c = 2 * w + i;
                int row = ((c & 1) << 6) + lane;
                int R = r0 + row; int b = R / TOUT, t = R - b * TOUT;
                gl16((const u16*)Asrc + ((size_t)b * TIN + t) * 512 + k0 + (c >> 1) * 8,
                     AsF + c * 512);
            }
        } else {
#pragma unroll
            for (int j = 0; j < 16; ++j) {
                int k = k0 + sq + j;
                float vin = 0.f;
                if (k < 396) vin = apf[k0 + j];
                int col = sq + j;
                AsF[(col >> 3) * 1024 + sr * 8 + (col & 7)] = f2bf(vin * 1e-3f);
            }
        }
#pragma unroll
        for (int i = 0; i < 2; ++i) {
            int c = 2 * w + i;
            int row = ((c & 1) << 6) + lane;
            gl16(Bt + (size_t)(n0 + row) * K + k0 + (c >> 1) * 8, BsF + c * 512);
        }
        __syncthreads();
        bf16x8 a[4], b[4];
#pragma unroll
        for (int m = 0; m < 4; ++m) a[m] = *(const bf16x8*)&AsF[grp * 1024 + (wr + m * 16 + row16) * 8];
#pragma unroll
        for (int n = 0; n < 4; ++n) b[n] = *(const bf16x8*)&BsF[grp * 1024 + (wc + n * 16 + row16) * 8];
#pragma unroll
        for (int m = 0; m < 4; ++m)
#pragma unroll
            for (int n = 0; n < 4; ++n)
                acc[m][n] = __builtin_amdgcn_mfma_f32_16x16x32_bf16(a[m], b[n], acc[m][n], 0, 0, 0);
        __syncthreads();
    }
#pragma unroll
    for (int m = 0; m < 4; ++m) {
        int rb = r0 + wr + m * 16 + grp * 4;
#pragma unroll
        for (int n = 0; n < 4; ++n) {
            int c = n0 + wc + n * 16 + row16;
            if (c < Nvalid) {
#pragma unroll
                for (int j = 0; j < 4; ++j) {
                    float v = fmaxf(acc[m][n][j], 0.f);
                    if constexpr (EPI == 0) ((u16*)Cout)[(size_t)(rb + j) * ldc + c] = f2bf(v);
                    else                    ((float*)Cout)[(size_t)(rb + j) * ldc + c] = v;
                }
            }
        }
    }
}

// ---------------- attention weights: att[b,n] ----------------
__global__ __launch_bounds__(256) void att_kernel(const float* __restrict__ qT,
                                                  const float* __restrict__ kT,
                                                  float* __restrict__ att) {
    const int b = blockIdx.x, tid = threadIdx.x;
    __shared__ float part[256];
    __shared__ float sc[16];
    int n = tid >> 4, j = tid & 15;
    const float* q = qT + b * 512;
    const float* k = kT + b * 8192 + n * 512;
    float acc = 0.f;
    for (int d = j; d < 512; d += 16) acc += q[d] * k[d];
    part[tid] = acc;
    __syncthreads();
    if (tid < 16) {
        float s = 0.f;
        for (int jj = 0; jj < 16; ++jj) s += part[tid * 16 + jj];
        sc[tid] = s + 1e-15f;
    }
    __syncthreads();
    if (tid == 0) {
        float tot = 0.f;
        for (int nn = 0; nn < 16; ++nn) tot += sc[nn];
        float inv = 1.f / tot;
        for (int nn = 0; nn < 16; ++nn) att[b * 16 + nn] = sc[nn] * inv;
    }
}

// ---------------- build x : fp32 (b,66,40) + bf16 padded (b,66,64) ------------
__global__ __launch_bounds__(256) void xbuild(const float* __restrict__ src,
                                              const float* __restrict__ att,
                                              const float* __restrict__ dct20,
                                              float* __restrict__ x,
                                              u16* __restrict__ xbf) {
    const int b = blockIdx.x, tid = threadIdx.x;
    __shared__ float s_src[50 * 66];
    __shared__ float s_sacc[VL * 66];
    __shared__ float s_d[DCTN * VL];
    __shared__ float s_att[16];
    for (int i = tid; i < 3300; i += 256) s_src[i] = src[b * 3300 + i];
    for (int i = tid; i < DCTN * VL; i += 256) s_d[i] = dct20[i];
    if (tid < 16) s_att[tid] = att[b * 16 + tid];
    __syncthreads();
    for (int i = tid; i < VL * 66; i += 256) {
        int v = i / 66, f = i - (i / 66) * 66;
        float a = 0.f;
#pragma unroll
        for (int n = 0; n < 16; ++n) a += s_att[n] * s_src[(n + v) * 66 + f];
        s_sacc[i] = a;
    }
    __syncthreads();
    for (int i = tid; i < 66 * DCTN; i += 256) {
        int f = i / DCTN, kq = i - (i / DCTN) * DCTN;
        float din = 0.f, datt = 0.f;
        for (int v = 0; v < VL; ++v) {
            float dv = s_d[kq * VL + v];
            int t2 = (v < 10) ? (40 + v) : 49;
            din += dv * s_src[t2 * 66 + f];
            datt += dv * s_sacc[v * 66 + f];
        }
        x[b * 2640 + f * 40 + kq] = din;
        x[b * 2640 + f * 40 + 20 + kq] = datt;
        xbf[(size_t)b * 4224 + f * 64 + kq] = f2bf(din);
        xbf[(size_t)b * 4224 + f * 64 + 20 + kq] = f2bf(datt);
    }
    for (int i = tid; i < 66 * 24; i += 256) {
        int f = i / 24, kp = 40 + (i - (i / 24) * 24);
        xbf[(size_t)b * 4224 + f * 64 + kp] = 0;
    }
}

// ---------------- out[b,v,f] = sum_k dct20[k,v]*dctout[b,f,k] ----------------
__global__ __launch_bounds__(256) void final_out(const float* __restrict__ dctout,
                                                 const float* __restrict__ dct20,
                                                 float* __restrict__ out) {
    const int b = blockIdx.x, tid = threadIdx.x;
    __shared__ float ds[DCTN * VL];
    __shared__ float dos[66 * 20];
    for (int i = tid; i < DCTN * VL; i += 256) ds[i] = dct20[i];
    for (int i = tid; i < 1320; i += 256) dos[i] = dctout[(size_t)b * 1320 + i];
    __syncthreads();
    for (int o = tid; o < VL * 66; o += 256) {
        int v = o / 66, f = o - (o / 66) * 66;
        float acc = 0.f;
#pragma unroll
        for (int k = 0; k < DCTN; ++k) acc += ds[k * VL + v] * dos[f * 20 + k];
        out[(size_t)b * 2310 + o] = acc;
    }
}

extern "C" void kernel_launch(void* const* d_in, const int* in_sizes, int n_in,
                              void* d_out, int out_size, void* d_ws, size_t ws_size,
                              hipStream_t stream) {
    const float* src     = (const float*)d_in[0];
    const float* Wq1     = (const float*)d_in[1];
    const float* Wq2     = (const float*)d_in[2];
    const float* Wk1     = (const float*)d_in[3];
    const float* Wk2     = (const float*)d_in[4];
    const float* gc1_W   = (const float*)d_in[5];
    const float* gc1_att = (const float*)d_in[6];
    const float* gc1_b   = (const float*)d_in[7];
    const float* bn1_g   = (const float*)d_in[8];
    const float* bn1_b   = (const float*)d_in[9];
    const float* gcb_W   = (const float*)d_in[10];
    const float* gcb_att = (const float*)d_in[11];
    const float* gcb_b   = (const float*)d_in[12];
    const float* gcb_g   = (const float*)d_in[13];
    const float* gcb_be  = (const float*)d_in[14];
    const float* gc7_W   = (const float*)d_in[15];
    const float* gc7_att = (const float*)d_in[16];
    const float* gc7_b   = (const float*)d_in[17];
    float* out = (float*)d_out;

    unsigned char* base = (unsigned char*)d_ws;
    size_t off = 0;
    auto take = [&](size_t bytes) -> void* {
        void* p = base + off;
        off += (bytes + 255) & ~(size_t)255;
        return p;
    };
    u16*   yA     = (u16*)take((size_t)33792 * 512 * 2);
    u16*   yB     = (u16*)take((size_t)33792 * 512 * 2);
    float* xb     = (float*)take((size_t)512 * 2640 * 4);
    u16*   xbf    = (u16*)take((size_t)512 * 4224 * 2);
    float* dct20  = (float*)take(2800);
    float* dctout = (float*)take((size_t)512 * 1320 * 4);
    u16*   key1   = (u16*)take((size_t)512 * 20 * 512 * 2);
    u16*   q1     = (u16*)take((size_t)512 * 5 * 512 * 2);
    float* keyT   = (float*)take((size_t)8192 * 512 * 4);
    float* queryT = (float*)take((size_t)512 * 512 * 4);
    float* attw   = (float*)take((size_t)512 * 16 * 4);
    u16*   WtGcb  = (u16*)take((size_t)4 * 512 * 512 * 2);
    u16*   WtGc1  = (u16*)take((size_t)512 * 64 * 2);
    u16*   WtGc7  = (u16*)take((size_t)128 * 512 * 2);
    u16*   WtW1k  = (u16*)take((size_t)512 * 416 * 2);
    u16*   WtW1q  = (u16*)take((size_t)512 * 416 * 2);
    u16*   WtW2k  = (u16*)take((size_t)512 * 2560 * 2);
    u16*   WtW2q  = (u16*)take((size_t)512 * 2560 * 2);
    u16*   Abf    = (u16*)take((size_t)6 * 8320 * 2);

    dct_kernel<<<2, 384, 0, stream>>>(dct20);
    cvt_att<<<dim3(33, 6), 256, 0, stream>>>(gc1_att, gcb_att, gc7_att, Abf);
    cvt_gcb<<<dim3(1024, 4), 256, 0, stream>>>(gcb_W, WtGcb);
    cvt_gc1<<<128, 256, 0, stream>>>(gc1_W, WtGc1);
    cvt_gc7<<<256, 256, 0, stream>>>(gc7_W, WtGc7);
    cvt_w1<<<832, 256, 0, stream>>>(Wk1, WtW1k);
    cvt_w1<<<832, 256, 0, stream>>>(Wq1, WtW1q);
    cvt_w2<<<5120, 256, 0, stream>>>(Wk2, WtW2k);
    cvt_w2<<<5120, 256, 0, stream>>>(Wq2, WtW2q);

    // conv stacks (im2col is a strided view -> read inputs directly)
    gemm_uni<2, 0, 20, 25, 0><<<dim3(80, 4), 256, 0, stream>>>(
        src, WtW1k, key1, 10240, 416, 512, 512);
    gemm_uni<2, 0, 5, 10, 40><<<dim3(20, 4), 256, 0, stream>>>(
        src, WtW1q, q1, 2560, 416, 512, 512);
    gemm_uni<1, 1, 16, 20, 0><<<dim3(64, 4), 256, 0, stream>>>(
        key1, WtW2k, keyT, 8192, 2560, 512, 512);
    gemm_uni<1, 1, 1, 5, 0><<<dim3(4, 4), 256, 0, stream>>>(
        q1, WtW2q, queryT, 512, 2560, 512, 512);
    att_kernel<<<BSZ, 256, 0, stream>>>(queryT, keyT, attw);
    xbuild<<<BSZ, 256, 0, stream>>>(src, attw, dct20, xb, xbf);

    // gc1: yA = tanh(bn(A1 @ (x @ W1) + b))
    gc_fused<2><<<dim3(256, 4), 256, 0, stream>>>(
        xbf, WtGc1, Abf, yA, 64, gc1_b, bn1_g, bn1_b, nullptr, nullptr);

    // stages
    for (int st = 0; st < 2; ++st) {
        const u16* W0 = WtGcb + (size_t)(st * 2 + 0) * 262144;
        const u16* W1 = WtGcb + (size_t)(st * 2 + 1) * 262144;
        const u16* A0 = Abf + (size_t)(1 + st * 2) * 8320;
        const u16* A1 = Abf + (size_t)(2 + st * 2) * 8320;
        const float* b0  = gcb_b + (size_t)(st * 2 + 0) * 512;
        const float* b1  = gcb_b + (size_t)(st * 2 + 1) * 512;
        const float* g0  = gcb_g + (size_t)(st * 2 + 0) * 33792;
        const float* g1  = gcb_g + (size_t)(st * 2 + 1) * 33792;
        const float* be0 = gcb_be + (size_t)(st * 2 + 0) * 33792;
        const float* be1 = gcb_be + (size_t)(st * 2 + 1) * 33792;
        gc_fused<2><<<dim3(256, 4), 256, 0, stream>>>(
            yA, W0, A0, yB, 512, b0, g0, be0, nullptr, nullptr);
        gc_fused<3><<<dim3(256, 4), 256, 0, stream>>>(
            yB, W1, A1, yA, 512, b1, g1, be1, yA, nullptr);
    }

    // gc7: dctout = A7 @ (y @ W7) + b7 + x  (first 20 cols)
    gc_fused<4><<<dim3(256, 1), 256, 0, stream>>>(
        yA, WtGc7, Abf + (size_t)5 * 8320, dctout, 512, gc7_b, nullptr, nullptr, nullptr, xb);
    final_out<<<BSZ, 256, 0, stream>>>(dctout, dct20, out);
}

// Round 8
// 769.636 us; speedup vs baseline: 1.2206x; 1.0794x over previous
//
#include <hip/hip_runtime.h>
#include <math.h>

#define PI_D 3.14159265358979323846

#define BSZ   512
#define NODE  66
#define VL    35
#define DCTN  20

static constexpr float BN_INVS = 0.99999500003749969f; // 1/sqrt(1+1e-5)

typedef unsigned short u16;
typedef unsigned int   u32;
using bf16x8 = __attribute__((ext_vector_type(8))) short;
using f32x4  = __attribute__((ext_vector_type(4))) float;

#define AS1 __attribute__((address_space(1)))
#define AS3 __attribute__((address_space(3)))

__device__ __forceinline__ void gl16(const u16* g, u16* l) {
    // async global->LDS DMA, 16B per lane; LDS dest = wave-uniform base + lane*16
    __builtin_amdgcn_global_load_lds((const AS1 u32*)g, (AS3 u32*)l, 16, 0, 0);
}

__device__ inline u16 f2bf(float f) {
    union { float f; u32 u; } v; v.f = f;
    u32 r = v.u + 0x7FFFu + ((v.u >> 16) & 1u);
    return (u16)(r >> 16);
}
__device__ inline float bf2f(u16 b) {
    union { u32 u; float f; } v; v.u = ((u32)b) << 16;
    return v.f;
}

// ---------------- dct20 (20 x 35), orthonormal DCT-II rows ----------------
__global__ void dct_kernel(float* __restrict__ dct20) {
    int i = blockIdx.x * blockDim.x + threadIdx.x;
    if (i < DCTN * VL) {
        int k = i / VL, v = i - k * VL;
        double w = (k == 0) ? sqrt(1.0 / VL) : sqrt(2.0 / VL);
        dct20[i] = (float)(w * cos(PI_D * (v + 0.5) * k / (double)VL));
    }
}

// ---------------- weight conversion / transpose to bf16 ----------------
__global__ void cvt_gcb(const float* __restrict__ W, u16* __restrict__ Wt) {
    int l = blockIdx.y;
    int i = blockIdx.x * 256 + threadIdx.x;
    int n = i >> 9, k = i & 511;
    Wt[(size_t)l * 262144 + i] = f2bf(W[(size_t)l * 262144 + (size_t)k * 512 + n]);
}
__global__ void cvt_gc1(const float* __restrict__ W, u16* __restrict__ Wt) {
    int i = blockIdx.x * 256 + threadIdx.x;
    int n = i >> 6, k = i & 63;
    Wt[i] = (k < 40) ? f2bf(W[k * 512 + n]) : (u16)0;
}
__global__ void cvt_gc7(const float* __restrict__ W, u16* __restrict__ Wt) {
    int i = blockIdx.x * 256 + threadIdx.x;
    int n = i >> 9, k = i & 511;
    Wt[i] = (n < 20) ? f2bf(W[k * 40 + n]) : (u16)0;
}
__global__ void cvt_w1(const float* __restrict__ W, u16* __restrict__ Wt) {
    int i = blockIdx.x * 256 + threadIdx.x;
    int d = i / 416, k = i - d * 416;
    float v = 0.f;
    if (k < 396) { int h = k / 66, c = k - h * 66; v = W[d * 396 + c * 6 + h]; }
    Wt[i] = f2bf(v);
}
__global__ void cvt_w2(const float* __restrict__ W, u16* __restrict__ Wt) {
    int i = blockIdx.x * 256 + threadIdx.x;
    int d = i / 2560, k = i - d * 2560;
    int h = k >> 9, c = k & 511;
    Wt[i] = f2bf(W[(size_t)d * 2560 + c * 5 + h]);
}
// A matrices (66x66) -> prepadded bf16 [6][80][104] (cols 66..103 zero)
__global__ void cvt_att(const float* __restrict__ gc1A, const float* __restrict__ gcbA,
                        const float* __restrict__ gc7A, u16* __restrict__ Abf) {
    int l = blockIdx.y;
    int i = blockIdx.x * 256 + threadIdx.x;
    if (i < 8320) {
        int r = i / 104, c = i - (i / 104) * 104;
        float v = 0.f;
        if (r < 66 && c < 66) {
            const float* A = (l == 0) ? gc1A : (l <= 4 ? gcbA + (size_t)(l - 1) * 4356 : gc7A);
            v = A[r * 66 + c];
        }
        Abf[(size_t)l * 8320 + i] = f2bf(v);
    }
}

// ---------------- fused GCN layer: y' = epi( A_g @ (Y @ W) ) ----------------
// Block = 2 batches (132 rows staged as 144) x 128 f-cols, 4 waves.
// K-loop is 2-phase ping-pong (T3-minimal): stage(next) via global_load_lds is
// issued BEFORE computing current buffer; ONE __syncthreads per iter (its
// implicit vmcnt(0) drain makes the next buffer visible). Double buffer =
// 2 x (A[4][144][8] + B[4][128][8]) = 17408 u16, aliased under zT[..19624).
// After the loop the same LDS is zT[f][152] for the A-mult phase.
// EPI: 2 = bn+tanh -> bf16 y ; 3 = bn+tanh+res -> bf16 y ; 4 = +bias+x -> fp32 dctout
template<int EPI>
__global__ __launch_bounds__(256) void gc_fused(const u16* __restrict__ Y,
                                                const u16* __restrict__ Wt,
                                                const u16* __restrict__ Ab,
                                                void* __restrict__ Yout, int K,
                                                const float* __restrict__ bias,
                                                const float* __restrict__ g,
                                                const float* __restrict__ be,
                                                const u16* __restrict__ yres,
                                                const float* __restrict__ xres) {
    __shared__ u16 smem[19624];          // 39.25 KB
    u16* zT = smem;                      // [129][152]+tail, aliases the dbuf

    const int tid = threadIdx.x;
    const int b0 = blockIdx.x * 2;
    const int n0 = blockIdx.y * 128;
    const int lane = tid & 63, w = tid >> 6;
    const int row16 = lane & 15, grp = lane >> 4;

    // stage one 32-K tile into buffer `buf` (A: 9x1KB chunks, B: 8x1KB chunks)
    auto stage = [&](int buf, int k0) {
        u16* A = smem + buf * 8704;
        u16* B = A + 4608;
        {
            int c = w;
            int flat = c * 1024 + lane * 16;
            int plane = flat / 2304;                 // 144*16B per plane
            int row = (flat - plane * 2304) >> 4;
            long grow = (long)b0 * 66 + row; if (grow > 33791) grow = 33791;
            gl16(Y + (size_t)grow * K + k0 + plane * 8, A + c * 512);
        }
        {
            int c = w + 4;
            int flat = c * 1024 + lane * 16;
            int plane = flat / 2304;
            int row = (flat - plane * 2304) >> 4;
            long grow = (long)b0 * 66 + row; if (grow > 33791) grow = 33791;
            gl16(Y + (size_t)grow * K + k0 + plane * 8, A + c * 512);
        }
        if (w == 0) {
            int c = 8;
            int flat = c * 1024 + lane * 16;
            int plane = flat / 2304;
            int row = (flat - plane * 2304) >> 4;
            long grow = (long)b0 * 66 + row; if (grow > 33791) grow = 33791;
            gl16(Y + (size_t)grow * K + k0 + plane * 8, A + c * 512);
        }
#pragma unroll
        for (int i = 0; i < 2; ++i) {
            int c = 2 * w + i;
            int row = ((c & 1) << 6) + lane;
            gl16(Wt + (size_t)(n0 + row) * K + k0 + (c >> 1) * 8, B + c * 512);
        }
    };

    stage(0, 0);
    __syncthreads();            // drains the prologue DMA

    f32x4 acc[9][2] = {};
    int cur = 0;
    for (int k0 = 0; k0 < K; k0 += 32) {
        if (k0 + 32 < K) stage(cur ^ 1, k0 + 32);   // prefetch next tile
        const u16* AsF = smem + cur * 8704;
        const u16* BsF = AsF + 4608;
        const int aoff = grp * 1152 + row16 * 8;
        const int boff = grp * 1024 + (w * 32 + row16) * 8;
        bf16x8 b[2];
#pragma unroll
        for (int nt = 0; nt < 2; ++nt) b[nt] = *(const bf16x8*)&BsF[boff + nt * 128];
#pragma unroll
        for (int mc = 0; mc < 3; ++mc) {     // 3 chunks of 3 m-tiles
            bf16x8 a[3];
#pragma unroll
            for (int i = 0; i < 3; ++i) a[i] = *(const bf16x8*)&AsF[aoff + (mc * 3 + i) * 128];
#pragma unroll
            for (int i = 0; i < 3; ++i)
#pragma unroll
                for (int nt = 0; nt < 2; ++nt)
                    acc[mc * 3 + i][nt] = __builtin_amdgcn_mfma_f32_16x16x32_bf16(a[i], b[nt], acc[mc * 3 + i][nt], 0, 0, 0);
        }
        __syncthreads();        // implicit vmcnt(0): next buffer landed; cur free for overwrite
        cur ^= 1;
    }

    // zero zT pads: cols 66..71 & 138..151 (rows 0..127) + tail [19456,19624)
    for (int i = tid; i < 128 * 20; i += 256) {
        int f = i / 20, j = i - (i / 20) * 20;
        int c = (j < 6) ? (66 + j) : (132 + j);   // j>=6 -> 138..151
        zT[f * 152 + c] = 0;
    }
    for (int i = tid; i < 168; i += 256) zT[19456 + i] = 0;

    // pack t^T into zT (b1 shifted +6 -> base col 72)
#pragma unroll
    for (int mt = 0; mt < 9; ++mt) {
        int m = mt * 16 + grp * 4;
        if (m < 132) {
#pragma unroll
            for (int nt = 0; nt < 2; ++nt) {
                int f = w * 32 + nt * 16 + row16;
                u16 e0 = f2bf(acc[mt][nt][0]), e1 = f2bf(acc[mt][nt][1]);
                u16 e2 = f2bf(acc[mt][nt][2]), e3 = f2bf(acc[mt][nt][3]);
                if (m + 3 < 66 || m >= 66) {
                    int col = (m < 66) ? m : m + 6;
                    *(u32*)&zT[f * 152 + col]     = (u32)e0 | ((u32)e1 << 16);
                    *(u32*)&zT[f * 152 + col + 2] = (u32)e2 | ((u32)e3 << 16);
                } else { // m=64 straddle: 64,65 | 72,73
                    zT[f * 152 + 64] = e0; zT[f * 152 + 65] = e1;
                    zT[f * 152 + 72] = e2; zT[f * 152 + 73] = e3;
                }
            }
        }
    }

    // A fragments from global (L2-hot)
    bf16x8 aA[5][3];
#pragma unroll
    for (int mt = 0; mt < 5; ++mt)
#pragma unroll
        for (int k2 = 0; k2 < 3; ++k2)
            aA[mt][k2] = *(const bf16x8*)&Ab[(mt * 16 + row16) * 104 + k2 * 32 + grp * 8];
    __syncthreads();

    f32x4 acc2[2][5][2] = {};
#pragma unroll
    for (int bb = 0; bb < 2; ++bb) {
        const int base = bb * 72;
#pragma unroll
        for (int k2 = 0; k2 < 3; ++k2) {
            bf16x8 bz[2];
#pragma unroll
            for (int ft = 0; ft < 2; ++ft)
                bz[ft] = *(const bf16x8*)&zT[(w * 32 + ft * 16 + row16) * 152 + base + k2 * 32 + grp * 8];
#pragma unroll
            for (int mt = 0; mt < 5; ++mt)
#pragma unroll
                for (int ft = 0; ft < 2; ++ft)
                    acc2[bb][mt][ft] = __builtin_amdgcn_mfma_f32_16x16x32_bf16(aA[mt][k2], bz[ft], acc2[bb][mt][ft], 0, 0, 0);
        }
    }

    // epilogue
#pragma unroll
    for (int bb = 0; bb < 2; ++bb) {
        const int bidx = b0 + bb;
#pragma unroll
        for (int mt = 0; mt < 5; ++mt) {
            int nb = mt * 16 + grp * 4;
#pragma unroll
            for (int ft = 0; ft < 2; ++ft) {
                int c = n0 + w * 32 + ft * 16 + row16;
#pragma unroll
                for (int j = 0; j < 4; ++j) {
                    int n = nb + j;
                    if (n < 66) {
                        float v = acc2[bb][mt][ft][j];
                        if constexpr (EPI == 4) {
                            if (c < 20)
                                ((float*)Yout)[(size_t)bidx * 1320 + n * 20 + c] =
                                    v + bias[c] + xres[(size_t)bidx * 2640 + n * 40 + c];
                        } else {
                            int gi = n * 512 + c;
                            float z = v + bias[c];
                            float t = tanhf(z * (g[gi] * BN_INVS) + be[gi]);
                            if constexpr (EPI == 3) t += bf2f(yres[((size_t)bidx * 66 + n) * 512 + c]);
                            ((u16*)Yout)[((size_t)bidx * 66 + n) * 512 + c] = f2bf(t);
                        }
                    }
                }
            }
        }
    }
}

// ---------------- unified bf16 MFMA GEMM (conv stacks), 2-phase ping-pong ----
// Per-buffer: A[4][128][8] + B[4][128][8] = 8192 u16; dbuf = 32 KB.
// ASRC: 1 = bf16 conv window (in[b][TIN][512], k-contig);
//       2 = fp32 src window (src[b][50][66], k<396 guard, *1e-3) - manual stage
// EPI:  0 = relu -> bf16 (ldc); 1 = relu -> fp32 (ldc)
template<int ASRC, int EPI, int TOUT, int TIN, int T0>
__global__ __launch_bounds__(256) void gemm_uni(const void* __restrict__ Asrc,
                                                const u16* __restrict__ Bt,
                                                void* __restrict__ Cout,
                                                int M, int K, int Nvalid, int ldc) {
    __shared__ u16 smem[16384];
    const int tid = threadIdx.x;
    const int r0 = blockIdx.x * 128, n0 = blockIdx.y * 128;
    const int lane = tid & 63, w = tid >> 6;
    const int wr = (w >> 1) * 64, wc = (w & 1) * 64;
    const int row16 = lane & 15, grp = lane >> 4;
    const int sr = tid >> 1, sq = (tid & 1) * 16;

    const float* apf = nullptr;
    if constexpr (ASRC == 2) {
        int R = r0 + sr; int b = R / TOUT, t = R - b * TOUT;
        apf = (const float*)Asrc + (size_t)b * 3300 + (T0 + t) * 66 + sq;
    }

    auto stage = [&](int buf, int k0) {
        u16* A = smem + buf * 8192;
        u16* B = A + 4096;
        if constexpr (ASRC == 1) {
#pragma unroll
            for (int i = 0; i < 2; ++i) {
                int c = 2 * w + i;
                int row = ((c & 1) << 6) + lane;
                int R = r0 + row; int b = R / TOUT, t = R - b * TOUT;
                gl16((const u16*)Asrc + ((size_t)b * TIN + t) * 512 + k0 + (c >> 1) * 8,
                     A + c * 512);
            }
        } else {
#pragma unroll
            for (int j = 0; j < 16; ++j) {
                int k = k0 + sq + j;
                float vin = 0.f;
                if (k < 396) vin = apf[k0 + j];
                int col = sq + j;
                A[(col >> 3) * 1024 + sr * 8 + (col & 7)] = f2bf(vin * 1e-3f);
            }
        }
#pragma unroll
        for (int i = 0; i < 2; ++i) {
            int c = 2 * w + i;
            int row = ((c & 1) << 6) + lane;
            gl16(Bt + (size_t)(n0 + row) * K + k0 + (c >> 1) * 8, B + c * 512);
        }
    };

    stage(0, 0);
    __syncthreads();

    f32x4 acc[4][4] = {};
    int cur = 0;
    for (int k0 = 0; k0 < K; k0 += 32) {
        if (k0 + 32 < K) stage(cur ^ 1, k0 + 32);
        const u16* AsF = smem + cur * 8192;
        const u16* BsF = AsF + 4096;
        bf16x8 a[4], b[4];
#pragma unroll
        for (int m = 0; m < 4; ++m) a[m] = *(const bf16x8*)&AsF[grp * 1024 + (wr + m * 16 + row16) * 8];
#pragma unroll
        for (int n = 0; n < 4; ++n) b[n] = *(const bf16x8*)&BsF[grp * 1024 + (wc + n * 16 + row16) * 8];
#pragma unroll
        for (int m = 0; m < 4; ++m)
#pragma unroll
            for (int n = 0; n < 4; ++n)
                acc[m][n] = __builtin_amdgcn_mfma_f32_16x16x32_bf16(a[m], b[n], acc[m][n], 0, 0, 0);
        __syncthreads();
        cur ^= 1;
    }
#pragma unroll
    for (int m = 0; m < 4; ++m) {
        int rb = r0 + wr + m * 16 + grp * 4;
#pragma unroll
        for (int n = 0; n < 4; ++n) {
            int c = n0 + wc + n * 16 + row16;
            if (c < Nvalid) {
#pragma unroll
                for (int j = 0; j < 4; ++j) {
                    float v = fmaxf(acc[m][n][j], 0.f);
                    if constexpr (EPI == 0) ((u16*)Cout)[(size_t)(rb + j) * ldc + c] = f2bf(v);
                    else                    ((float*)Cout)[(size_t)(rb + j) * ldc + c] = v;
                }
            }
        }
    }
}

// ---------------- attention weights: att[b,n] ----------------
__global__ __launch_bounds__(256) void att_kernel(const float* __restrict__ qT,
                                                  const float* __restrict__ kT,
                                                  float* __restrict__ att) {
    const int b = blockIdx.x, tid = threadIdx.x;
    __shared__ float part[256];
    __shared__ float sc[16];
    int n = tid >> 4, j = tid & 15;
    const float* q = qT + b * 512;
    const float* k = kT + b * 8192 + n * 512;
    float acc = 0.f;
    for (int d = j; d < 512; d += 16) acc += q[d] * k[d];
    part[tid] = acc;
    __syncthreads();
    if (tid < 16) {
        float s = 0.f;
        for (int jj = 0; jj < 16; ++jj) s += part[tid * 16 + jj];
        sc[tid] = s + 1e-15f;
    }
    __syncthreads();
    if (tid == 0) {
        float tot = 0.f;
        for (int nn = 0; nn < 16; ++nn) tot += sc[nn];
        float inv = 1.f / tot;
        for (int nn = 0; nn < 16; ++nn) att[b * 16 + nn] = sc[nn] * inv;
    }
}

// ---------------- build x : fp32 (b,66,40) + bf16 padded (b,66,64) ------------
__global__ __launch_bounds__(256) void xbuild(const float* __restrict__ src,
                                              const float* __restrict__ att,
                                              const float* __restrict__ dct20,
                                              float* __restrict__ x,
                                              u16* __restrict__ xbf) {
    const int b = blockIdx.x, tid = threadIdx.x;
    __shared__ float s_src[50 * 66];
    __shared__ float s_sacc[VL * 66];
    __shared__ float s_d[DCTN * VL];
    __shared__ float s_att[16];
    for (int i = tid; i < 3300; i += 256) s_src[i] = src[b * 3300 + i];
    for (int i = tid; i < DCTN * VL; i += 256) s_d[i] = dct20[i];
    if (tid < 16) s_att[tid] = att[b * 16 + tid];
    __syncthreads();
    for (int i = tid; i < VL * 66; i += 256) {
        int v = i / 66, f = i - (i / 66) * 66;
        float a = 0.f;
#pragma unroll
        for (int n = 0; n < 16; ++n) a += s_att[n] * s_src[(n + v) * 66 + f];
        s_sacc[i] = a;
    }
    __syncthreads();
    for (int i = tid; i < 66 * DCTN; i += 256) {
        int f = i / DCTN, kq = i - (i / DCTN) * DCTN;
        float din = 0.f, datt = 0.f;
        for (int v = 0; v < VL; ++v) {
            float dv = s_d[kq * VL + v];
            int t2 = (v < 10) ? (40 + v) : 49;
            din += dv * s_src[t2 * 66 + f];
            datt += dv * s_sacc[v * 66 + f];
        }
        x[b * 2640 + f * 40 + kq] = din;
        x[b * 2640 + f * 40 + 20 + kq] = datt;
        xbf[(size_t)b * 4224 + f * 64 + kq] = f2bf(din);
        xbf[(size_t)b * 4224 + f * 64 + 20 + kq] = f2bf(datt);
    }
    for (int i = tid; i < 66 * 24; i += 256) {
        int f = i / 24, kp = 40 + (i - (i / 24) * 24);
        xbf[(size_t)b * 4224 + f * 64 + kp] = 0;
    }
}

// ---------------- out[b,v,f] = sum_k dct20[k,v]*dctout[b,f,k] ----------------
__global__ __launch_bounds__(256) void final_out(const float* __restrict__ dctout,
                                                 const float* __restrict__ dct20,
                                                 float* __restrict__ out) {
    const int b = blockIdx.x, tid = threadIdx.x;
    __shared__ float ds[DCTN * VL];
    __shared__ float dos[66 * 20];
    for (int i = tid; i < DCTN * VL; i += 256) ds[i] = dct20[i];
    for (int i = tid; i < 1320; i += 256) dos[i] = dctout[(size_t)b * 1320 + i];
    __syncthreads();
    for (int o = tid; o < VL * 66; o += 256) {
        int v = o / 66, f = o - (o / 66) * 66;
        float acc = 0.f;
#pragma unroll
        for (int k = 0; k < DCTN; ++k) acc += ds[k * VL + v] * dos[f * 20 + k];
        out[(size_t)b * 2310 + o] = acc;
    }
}

extern "C" void kernel_launch(void* const* d_in, const int* in_sizes, int n_in,
                              void* d_out, int out_size, void* d_ws, size_t ws_size,
                              hipStream_t stream) {
    const float* src     = (const float*)d_in[0];
    const float* Wq1     = (const float*)d_in[1];
    const float* Wq2     = (const float*)d_in[2];
    const float* Wk1     = (const float*)d_in[3];
    const float* Wk2     = (const float*)d_in[4];
    const float* gc1_W   = (const float*)d_in[5];
    const float* gc1_att = (const float*)d_in[6];
    const float* gc1_b   = (const float*)d_in[7];
    const float* bn1_g   = (const float*)d_in[8];
    const float* bn1_b   = (const float*)d_in[9];
    const float* gcb_W   = (const float*)d_in[10];
    const float* gcb_att = (const float*)d_in[11];
    const float* gcb_b   = (const float*)d_in[12];
    const float* gcb_g   = (const float*)d_in[13];
    const float* gcb_be  = (const float*)d_in[14];
    const float* gc7_W   = (const float*)d_in[15];
    const float* gc7_att = (const float*)d_in[16];
    const float* gc7_b   = (const float*)d_in[17];
    float* out = (float*)d_out;

    unsigned char* base = (unsigned char*)d_ws;
    size_t off = 0;
    auto take = [&](size_t bytes) -> void* {
        void* p = base + off;
        off += (bytes + 255) & ~(size_t)255;
        return p;
    };
    u16*   yA     = (u16*)take((size_t)33792 * 512 * 2);
    u16*   yB     = (u16*)take((size_t)33792 * 512 * 2);
    float* xb     = (float*)take((size_t)512 * 2640 * 4);
    u16*   xbf    = (u16*)take((size_t)512 * 4224 * 2);
    float* dct20  = (float*)take(2800);
    float* dctout = (float*)take((size_t)512 * 1320 * 4);
    u16*   key1   = (u16*)take((size_t)512 * 20 * 512 * 2);
    u16*   q1     = (u16*)take((size_t)512 * 5 * 512 * 2);
    float* keyT   = (float*)take((size_t)8192 * 512 * 4);
    float* queryT = (float*)take((size_t)512 * 512 * 4);
    float* attw   = (float*)take((size_t)512 * 16 * 4);
    u16*   WtGcb  = (u16*)take((size_t)4 * 512 * 512 * 2);
    u16*   WtGc1  = (u16*)take((size_t)512 * 64 * 2);
    u16*   WtGc7  = (u16*)take((size_t)128 * 512 * 2);
    u16*   WtW1k  = (u16*)take((size_t)512 * 416 * 2);
    u16*   WtW1q  = (u16*)take((size_t)512 * 416 * 2);
    u16*   WtW2k  = (u16*)take((size_t)512 * 2560 * 2);
    u16*   WtW2q  = (u16*)take((size_t)512 * 2560 * 2);
    u16*   Abf    = (u16*)take((size_t)6 * 8320 * 2);

    dct_kernel<<<2, 384, 0, stream>>>(dct20);
    cvt_att<<<dim3(33, 6), 256, 0, stream>>>(gc1_att, gcb_att, gc7_att, Abf);
    cvt_gcb<<<dim3(1024, 4), 256, 0, stream>>>(gcb_W, WtGcb);
    cvt_gc1<<<128, 256, 0, stream>>>(gc1_W, WtGc1);
    cvt_gc7<<<256, 256, 0, stream>>>(gc7_W, WtGc7);
    cvt_w1<<<832, 256, 0, stream>>>(Wk1, WtW1k);
    cvt_w1<<<832, 256, 0, stream>>>(Wq1, WtW1q);
    cvt_w2<<<5120, 256, 0, stream>>>(Wk2, WtW2k);
    cvt_w2<<<5120, 256, 0, stream>>>(Wq2, WtW2q);

    // conv stacks (im2col is a strided view -> read inputs directly)
    gemm_uni<2, 0, 20, 25, 0><<<dim3(80, 4), 256, 0, stream>>>(
        src, WtW1k, key1, 10240, 416, 512, 512);
    gemm_uni<2, 0, 5, 10, 40><<<dim3(20, 4), 256, 0, stream>>>(
        src, WtW1q, q1, 2560, 416, 512, 512);
    gemm_uni<1, 1, 16, 20, 0><<<dim3(64, 4), 256, 0, stream>>>(
        key1, WtW2k, keyT, 8192, 2560, 512, 512);
    gemm_uni<1, 1, 1, 5, 0><<<dim3(4, 4), 256, 0, stream>>>(
        q1, WtW2q, queryT, 512, 2560, 512, 512);
    att_kernel<<<BSZ, 256, 0, stream>>>(queryT, keyT, attw);
    xbuild<<<BSZ, 256, 0, stream>>>(src, attw, dct20, xb, xbf);

    // gc1: yA = tanh(bn(A1 @ (x @ W1) + b))
    gc_fused<2><<<dim3(256, 4), 256, 0, stream>>>(
        xbf, WtGc1, Abf, yA, 64, gc1_b, bn1_g, bn1_b, nullptr, nullptr);

    // stages
    for (int st = 0; st < 2; ++st) {
        const u16* W0 = WtGcb + (size_t)(st * 2 + 0) * 262144;
        const u16* W1 = WtGcb + (size_t)(st * 2 + 1) * 262144;
        const u16* A0 = Abf + (size_t)(1 + st * 2) * 8320;
        const u16* A1 = Abf + (size_t)(2 + st * 2) * 8320;
        const float* b0  = gcb_b + (size_t)(st * 2 + 0) * 512;
        const float* b1  = gcb_b + (size_t)(st * 2 + 1) * 512;
        const float* g0  = gcb_g + (size_t)(st * 2 + 0) * 33792;
        const float* g1  = gcb_g + (size_t)(st * 2 + 1) * 33792;
        const float* be0 = gcb_be + (size_t)(st * 2 + 0) * 33792;
        const float* be1 = gcb_be + (size_t)(st * 2 + 1) * 33792;
        gc_fused<2><<<dim3(256, 4), 256, 0, stream>>>(
            yA, W0, A0, yB, 512, b0, g0, be0, nullptr, nullptr);
        gc_fused<3><<<dim3(256, 4), 256, 0, stream>>>(
            yB, W1, A1, yA, 512, b1, g1, be1, yA, nullptr);
    }

    // gc7: dctout = A7 @ (y @ W7) + b7 + x  (first 20 cols)
    gc_fused<4><<<dim3(256, 1), 256, 0, stream>>>(
        yA, WtGc7, Abf + (size_t)5 * 8320, dctout, 512, gc7_b, nullptr, nullptr, nullptr, xb);
    final_out<<<BSZ, 256, 0, stream>>>(dctout, dct20, out);
}

// Round 9
// 745.834 us; speedup vs baseline: 1.2596x; 1.0319x over previous
//
#include <hip/hip_runtime.h>
#include <math.h>

#define PI_D 3.14159265358979323846

#define BSZ   512
#define NODE  66
#define VL    35
#define DCTN  20

static constexpr float BN_INVS = 0.99999500003749969f; // 1/sqrt(1+1e-5)

typedef unsigned short u16;
typedef unsigned int   u32;
using bf16x8 = __attribute__((ext_vector_type(8))) short;
using f32x4  = __attribute__((ext_vector_type(4))) float;

#define AS1 __attribute__((address_space(1)))
#define AS3 __attribute__((address_space(3)))

__device__ __forceinline__ void gl16(const u16* g, u16* l) {
    // async global->LDS DMA, 16B per lane; LDS dest = wave-uniform base + lane*16
    __builtin_amdgcn_global_load_lds((const AS1 u32*)g, (AS3 u32*)l, 16, 0, 0);
}

__device__ inline u16 f2bf(float f) {
    union { float f; u32 u; } v; v.f = f;
    u32 r = v.u + 0x7FFFu + ((v.u >> 16) & 1u);
    return (u16)(r >> 16);
}
__device__ inline float bf2f(u16 b) {
    union { u32 u; float f; } v; v.u = ((u32)b) << 16;
    return v.f;
}

// ---------------- dct20 (20 x 35), orthonormal DCT-II rows ----------------
__global__ void dct_kernel(float* __restrict__ dct20) {
    int i = blockIdx.x * blockDim.x + threadIdx.x;
    if (i < DCTN * VL) {
        int k = i / VL, v = i - k * VL;
        double w = (k == 0) ? sqrt(1.0 / VL) : sqrt(2.0 / VL);
        dct20[i] = (float)(w * cos(PI_D * (v + 0.5) * k / (double)VL));
    }
}

// ---------------- weight conversion / transpose to bf16 ----------------
__global__ void cvt_gcb(const float* __restrict__ W, u16* __restrict__ Wt) {
    int l = blockIdx.y;
    int i = blockIdx.x * 256 + threadIdx.x;
    int n = i >> 9, k = i & 511;
    Wt[(size_t)l * 262144 + i] = f2bf(W[(size_t)l * 262144 + (size_t)k * 512 + n]);
}
__global__ void cvt_gc1(const float* __restrict__ W, u16* __restrict__ Wt) {
    int i = blockIdx.x * 256 + threadIdx.x;
    int n = i >> 6, k = i & 63;
    Wt[i] = (k < 40) ? f2bf(W[k * 512 + n]) : (u16)0;
}
__global__ void cvt_gc7(const float* __restrict__ W, u16* __restrict__ Wt) {
    int i = blockIdx.x * 256 + threadIdx.x;
    int n = i >> 9, k = i & 511;
    Wt[i] = (n < 20) ? f2bf(W[k * 40 + n]) : (u16)0;
}
__global__ void cvt_w1(const float* __restrict__ W, u16* __restrict__ Wt) {
    int i = blockIdx.x * 256 + threadIdx.x;
    int d = i / 416, k = i - d * 416;
    float v = 0.f;
    if (k < 396) { int h = k / 66, c = k - h * 66; v = W[d * 396 + c * 6 + h]; }
    Wt[i] = f2bf(v);
}
__global__ void cvt_w2(const float* __restrict__ W, u16* __restrict__ Wt) {
    int i = blockIdx.x * 256 + threadIdx.x;
    int d = i / 2560, k = i - d * 2560;
    int h = k >> 9, c = k & 511;
    Wt[i] = f2bf(W[(size_t)d * 2560 + c * 5 + h]);
}
// A matrices (66x66) -> prepadded bf16 [6][80][104] (cols 66..103 zero)
__global__ void cvt_att(const float* __restrict__ gc1A, const float* __restrict__ gcbA,
                        const float* __restrict__ gc7A, u16* __restrict__ Abf) {
    int l = blockIdx.y;
    int i = blockIdx.x * 256 + threadIdx.x;
    if (i < 8320) {
        int r = i / 104, c = i - (i / 104) * 104;
        float v = 0.f;
        if (r < 66 && c < 66) {
            const float* A = (l == 0) ? gc1A : (l <= 4 ? gcbA + (size_t)(l - 1) * 4356 : gc7A);
            v = A[r * 66 + c];
        }
        Abf[(size_t)l * 8320 + i] = f2bf(v);
    }
}

// ---------------- fused GCN layer: y' = epi( A_g @ (Y @ W) ) ----------------
// ONE batch per block (66 rows staged as 80) x 128 f-cols, 4 waves, grid 2048.
// Small accumulators (acc[5][2] + acc2[5][2]) keep regs ~90-100 -> ~5 waves/SIMD.
// K-loop: 2-phase ping-pong, dbuf 2 x (A[4][80][8] + B[4][128][8]) = 26 KB;
// after the loop the same LDS is zT[128][104] (t^T bf16, cols 66..95 zeroed so
// A's zero-pad annihilates them). Phase 2: A(80x96pad) @ zT, aA loaded per-k2.
// EPI: 2 = bn+tanh -> bf16 y ; 3 = bn+tanh+res -> bf16 y ; 4 = +bias+x -> fp32 dctout
template<int EPI>
__global__ __launch_bounds__(256) void gc_fused(const u16* __restrict__ Y,
                                                const u16* __restrict__ Wt,
                                                const u16* __restrict__ Ab,
                                                void* __restrict__ Yout, int K,
                                                const float* __restrict__ bias,
                                                const float* __restrict__ g,
                                                const float* __restrict__ be,
                                                const u16* __restrict__ yres,
                                                const float* __restrict__ xres) {
    __shared__ u16 smem[13312];          // 26 KB
    u16* zT = smem;                      // [128][104], aliases the dbuf

    const int tid = threadIdx.x;
    const int b0 = blockIdx.x;
    const int n0 = blockIdx.y * 128;
    const int lane = tid & 63, w = tid >> 6;
    const int row16 = lane & 15, grp = lane >> 4;

    auto stage = [&](int buf, int k0) {
        u16* A = smem + buf * 6656;
        u16* B = A + 2560;
        // A: 5 chunks of 1KB over [4][80][8] (plane = 80 rows x 16B = 1280B)
        {
            int c = w;
            int flat = c * 1024 + lane * 16;
            int plane = flat / 1280;
            int row = (flat - plane * 1280) >> 4;
            long grow = (long)b0 * 66 + row; if (grow > 33791) grow = 33791;
            gl16(Y + (size_t)grow * K + k0 + plane * 8, A + c * 512);
        }
        if (w == 0) {
            int c = 4;
            int flat = c * 1024 + lane * 16;
            int plane = flat / 1280;
            int row = (flat - plane * 1280) >> 4;
            long grow = (long)b0 * 66 + row; if (grow > 33791) grow = 33791;
            gl16(Y + (size_t)grow * K + k0 + plane * 8, A + c * 512);
        }
        // B: 8 chunks over [4][128][8]
#pragma unroll
        for (int i = 0; i < 2; ++i) {
            int c = 2 * w + i;
            int row = ((c & 1) << 6) + lane;
            gl16(Wt + (size_t)(n0 + row) * K + k0 + (c >> 1) * 8, B + c * 512);
        }
    };

    stage(0, 0);
    __syncthreads();

    f32x4 acc[5][2] = {};
    int cur = 0;
    for (int k0 = 0; k0 < K; k0 += 32) {
        if (k0 + 32 < K) stage(cur ^ 1, k0 + 32);   // prefetch next tile
        const u16* AsF = smem + cur * 6656;
        const u16* BsF = AsF + 2560;
        const int aoff = grp * 640 + row16 * 8;           // plane*80*8 + row*8
        const int boff = grp * 1024 + (w * 32 + row16) * 8;
        bf16x8 a[5], b[2];
#pragma unroll
        for (int nt = 0; nt < 2; ++nt) b[nt] = *(const bf16x8*)&BsF[boff + nt * 128];
#pragma unroll
        for (int mt = 0; mt < 5; ++mt) a[mt] = *(const bf16x8*)&AsF[aoff + mt * 128];
#pragma unroll
        for (int mt = 0; mt < 5; ++mt)
#pragma unroll
            for (int nt = 0; nt < 2; ++nt)
                acc[mt][nt] = __builtin_amdgcn_mfma_f32_16x16x32_bf16(a[mt], b[nt], acc[mt][nt], 0, 0, 0);
        __syncthreads();        // drains prefetch (vmcnt0) + protects buffer reuse
        cur ^= 1;
    }

    // zero zT cols 66..95 (phase-2 reads span cols 0..95)
    for (int i = tid; i < 128 * 30; i += 256) {
        int f = i / 30, j = i - (i / 30) * 30;
        zT[f * 104 + 66 + j] = 0;
    }

    // pack t^T into zT[128][104]
#pragma unroll
    for (int mt = 0; mt < 5; ++mt) {
        int m = mt * 16 + grp * 4;
        if (m < 66) {
#pragma unroll
            for (int nt = 0; nt < 2; ++nt) {
                int f = w * 32 + nt * 16 + row16;
                u16 e0 = f2bf(acc[mt][nt][0]), e1 = f2bf(acc[mt][nt][1]);
                u16 e2 = f2bf(acc[mt][nt][2]), e3 = f2bf(acc[mt][nt][3]);
                if (m < 64) {
                    *(u32*)&zT[f * 104 + m]     = (u32)e0 | ((u32)e1 << 16);
                    *(u32*)&zT[f * 104 + m + 2] = (u32)e2 | ((u32)e3 << 16);
                } else { // m == 64: only cols 64,65 are real
                    *(u32*)&zT[f * 104 + 64] = (u32)e0 | ((u32)e1 << 16);
                }
            }
        }
    }
    __syncthreads();

    f32x4 acc2[5][2] = {};
#pragma unroll
    for (int k2 = 0; k2 < 3; ++k2) {
        bf16x8 aA[5], bz[2];
#pragma unroll
        for (int mt = 0; mt < 5; ++mt)
            aA[mt] = *(const bf16x8*)&Ab[(mt * 16 + row16) * 104 + k2 * 32 + grp * 8];
#pragma unroll
        for (int ft = 0; ft < 2; ++ft)
            bz[ft] = *(const bf16x8*)&zT[(w * 32 + ft * 16 + row16) * 104 + k2 * 32 + grp * 8];
#pragma unroll
        for (int mt = 0; mt < 5; ++mt)
#pragma unroll
            for (int ft = 0; ft < 2; ++ft)
                acc2[mt][ft] = __builtin_amdgcn_mfma_f32_16x16x32_bf16(aA[mt], bz[ft], acc2[mt][ft], 0, 0, 0);
    }

    // epilogue
#pragma unroll
    for (int mt = 0; mt < 5; ++mt) {
        int nb = mt * 16 + grp * 4;
#pragma unroll
        for (int ft = 0; ft < 2; ++ft) {
            int c = n0 + w * 32 + ft * 16 + row16;
#pragma unroll
            for (int j = 0; j < 4; ++j) {
                int n = nb + j;
                if (n < 66) {
                    float v = acc2[mt][ft][j];
                    if constexpr (EPI == 4) {
                        if (c < 20)
                            ((float*)Yout)[(size_t)b0 * 1320 + n * 20 + c] =
                                v + bias[c] + xres[(size_t)b0 * 2640 + n * 40 + c];
                    } else {
                        int gi = n * 512 + c;
                        float z = v + bias[c];
                        float t = tanhf(z * (g[gi] * BN_INVS) + be[gi]);
                        if constexpr (EPI == 3) t += bf2f(yres[((size_t)b0 * 66 + n) * 512 + c]);
                        ((u16*)Yout)[((size_t)b0 * 66 + n) * 512 + c] = f2bf(t);
                    }
                }
            }
        }
    }
}

// ---------------- unified bf16 MFMA GEMM (conv stacks), 64x64 tiles ----------
// 4 waves in 2x2, each 32x32 (acc[2][2]); dbuf 2 x (A[4][64][8]+B[4][64][8]) = 16KB.
// 2-phase ping-pong with global_load_lds.
// ASRC: 1 = bf16 conv window (in[b][TIN][512], k-contig);
//       2 = fp32 src window (src[b][50][66], k<396 guard, *1e-3) - manual stage
// EPI:  0 = relu -> bf16 (ldc); 1 = relu -> fp32 (ldc)
template<int ASRC, int EPI, int TOUT, int TIN, int T0>
__global__ __launch_bounds__(256) void gemm_uni(const void* __restrict__ Asrc,
                                                const u16* __restrict__ Bt,
                                                void* __restrict__ Cout,
                                                int M, int K, int Nvalid, int ldc) {
    __shared__ u16 smem[8192];
    const int tid = threadIdx.x;
    const int r0 = blockIdx.x * 64, n0 = blockIdx.y * 64;
    const int lane = tid & 63, w = tid >> 6;
    const int wr = (w >> 1) * 32, wc = (w & 1) * 32;
    const int row16 = lane & 15, grp = lane >> 4;

    const float* apf = nullptr;
    const int sr2 = tid >> 2, sq2 = (tid & 3) * 8;
    if constexpr (ASRC == 2) {
        int R = r0 + sr2; int b = R / TOUT, t = R - b * TOUT;
        apf = (const float*)Asrc + (size_t)b * 3300 + (T0 + t) * 66 + sq2;
    }

    auto stage = [&](int buf, int k0) {
        u16* A = smem + buf * 4096;
        u16* B = A + 2048;
        if constexpr (ASRC == 1) {
            int R = r0 + lane; int b = R / TOUT, t = R - b * TOUT;
            gl16((const u16*)Asrc + ((size_t)b * TIN + t) * 512 + k0 + w * 8, A + w * 512);
        } else {
#pragma unroll
            for (int j = 0; j < 8; ++j) {
                int k = k0 + sq2 + j;
                float vin = 0.f;
                if (k < 396) vin = apf[k0 + j];
                A[(sq2 >> 3) * 512 + sr2 * 8 + j] = f2bf(vin * 1e-3f);
            }
        }
        gl16(Bt + (size_t)(n0 + lane) * K + k0 + w * 8, B + w * 512);
    };

    stage(0, 0);
    __syncthreads();

    f32x4 acc[2][2] = {};
    int cur = 0;
    for (int k0 = 0; k0 < K; k0 += 32) {
        if (k0 + 32 < K) stage(cur ^ 1, k0 + 32);
        const u16* AsF = smem + cur * 4096;
        const u16* BsF = AsF + 2048;
        bf16x8 a[2], b[2];
#pragma unroll
        for (int m = 0; m < 2; ++m) a[m] = *(const bf16x8*)&AsF[grp * 512 + (wr + m * 16 + row16) * 8];
#pragma unroll
        for (int n = 0; n < 2; ++n) b[n] = *(const bf16x8*)&BsF[grp * 512 + (wc + n * 16 + row16) * 8];
#pragma unroll
        for (int m = 0; m < 2; ++m)
#pragma unroll
            for (int n = 0; n < 2; ++n)
                acc[m][n] = __builtin_amdgcn_mfma_f32_16x16x32_bf16(a[m], b[n], acc[m][n], 0, 0, 0);
        __syncthreads();
        cur ^= 1;
    }
#pragma unroll
    for (int m = 0; m < 2; ++m) {
        int rb = r0 + wr + m * 16 + grp * 4;
#pragma unroll
        for (int n = 0; n < 2; ++n) {
            int c = n0 + wc + n * 16 + row16;
            if (c < Nvalid) {
#pragma unroll
                for (int j = 0; j < 4; ++j) {
                    float v = fmaxf(acc[m][n][j], 0.f);
                    if constexpr (EPI == 0) ((u16*)Cout)[(size_t)(rb + j) * ldc + c] = f2bf(v);
                    else                    ((float*)Cout)[(size_t)(rb + j) * ldc + c] = v;
                }
            }
        }
    }
}

// ---------------- attention weights: att[b,n] ----------------
__global__ __launch_bounds__(256) void att_kernel(const float* __restrict__ qT,
                                                  const float* __restrict__ kT,
                                                  float* __restrict__ att) {
    const int b = blockIdx.x, tid = threadIdx.x;
    __shared__ float part[256];
    __shared__ float sc[16];
    int n = tid >> 4, j = tid & 15;
    const float* q = qT + b * 512;
    const float* k = kT + b * 8192 + n * 512;
    float acc = 0.f;
    for (int d = j; d < 512; d += 16) acc += q[d] * k[d];
    part[tid] = acc;
    __syncthreads();
    if (tid < 16) {
        float s = 0.f;
        for (int jj = 0; jj < 16; ++jj) s += part[tid * 16 + jj];
        sc[tid] = s + 1e-15f;
    }
    __syncthreads();
    if (tid == 0) {
        float tot = 0.f;
        for (int nn = 0; nn < 16; ++nn) tot += sc[nn];
        float inv = 1.f / tot;
        for (int nn = 0; nn < 16; ++nn) att[b * 16 + nn] = sc[nn] * inv;
    }
}

// ---------------- build x : fp32 (b,66,40) + bf16 padded (b,66,64) ------------
__global__ __launch_bounds__(256) void xbuild(const float* __restrict__ src,
                                              const float* __restrict__ att,
                                              const float* __restrict__ dct20,
                                              float* __restrict__ x,
                                              u16* __restrict__ xbf) {
    const int b = blockIdx.x, tid = threadIdx.x;
    __shared__ float s_src[50 * 66];
    __shared__ float s_sacc[VL * 66];
    __shared__ float s_d[DCTN * VL];
    __shared__ float s_att[16];
    for (int i = tid; i < 3300; i += 256) s_src[i] = src[b * 3300 + i];
    for (int i = tid; i < DCTN * VL; i += 256) s_d[i] = dct20[i];
    if (tid < 16) s_att[tid] = att[b * 16 + tid];
    __syncthreads();
    for (int i = tid; i < VL * 66; i += 256) {
        int v = i / 66, f = i - (i / 66) * 66;
        float a = 0.f;
#pragma unroll
        for (int n = 0; n < 16; ++n) a += s_att[n] * s_src[(n + v) * 66 + f];
        s_sacc[i] = a;
    }
    __syncthreads();
    for (int i = tid; i < 66 * DCTN; i += 256) {
        int f = i / DCTN, kq = i - (i / DCTN) * DCTN;
        float din = 0.f, datt = 0.f;
        for (int v = 0; v < VL; ++v) {
            float dv = s_d[kq * VL + v];
            int t2 = (v < 10) ? (40 + v) : 49;
            din += dv * s_src[t2 * 66 + f];
            datt += dv * s_sacc[v * 66 + f];
        }
        x[b * 2640 + f * 40 + kq] = din;
        x[b * 2640 + f * 40 + 20 + kq] = datt;
        xbf[(size_t)b * 4224 + f * 64 + kq] = f2bf(din);
        xbf[(size_t)b * 4224 + f * 64 + 20 + kq] = f2bf(datt);
    }
    for (int i = tid; i < 66 * 24; i += 256) {
        int f = i / 24, kp = 40 + (i - (i / 24) * 24);
        xbf[(size_t)b * 4224 + f * 64 + kp] = 0;
    }
}

// ---------------- out[b,v,f] = sum_k dct20[k,v]*dctout[b,f,k] ----------------
__global__ __launch_bounds__(256) void final_out(const float* __restrict__ dctout,
                                                 const float* __restrict__ dct20,
                                                 float* __restrict__ out) {
    const int b = blockIdx.x, tid = threadIdx.x;
    __shared__ float ds[DCTN * VL];
    __shared__ float dos[66 * 20];
    for (int i = tid; i < DCTN * VL; i += 256) ds[i] = dct20[i];
    for (int i = tid; i < 1320; i += 256) dos[i] = dctout[(size_t)b * 1320 + i];
    __syncthreads();
    for (int o = tid; o < VL * 66; o += 256) {
        int v = o / 66, f = o - (o / 66) * 66;
        float acc = 0.f;
#pragma unroll
        for (int k = 0; k < DCTN; ++k) acc += ds[k * VL + v] * dos[f * 20 + k];
        out[(size_t)b * 2310 + o] = acc;
    }
}

extern "C" void kernel_launch(void* const* d_in, const int* in_sizes, int n_in,
                              void* d_out, int out_size, void* d_ws, size_t ws_size,
                              hipStream_t stream) {
    const float* src     = (const float*)d_in[0];
    const float* Wq1     = (const float*)d_in[1];
    const float* Wq2     = (const float*)d_in[2];
    const float* Wk1     = (const float*)d_in[3];
    const float* Wk2     = (const float*)d_in[4];
    const float* gc1_W   = (const float*)d_in[5];
    const float* gc1_att = (const float*)d_in[6];
    const float* gc1_b   = (const float*)d_in[7];
    const float* bn1_g   = (const float*)d_in[8];
    const float* bn1_b   = (const float*)d_in[9];
    const float* gcb_W   = (const float*)d_in[10];
    const float* gcb_att = (const float*)d_in[11];
    const float* gcb_b   = (const float*)d_in[12];
    const float* gcb_g   = (const float*)d_in[13];
    const float* gcb_be  = (const float*)d_in[14];
    const float* gc7_W   = (const float*)d_in[15];
    const float* gc7_att = (const float*)d_in[16];
    const float* gc7_b   = (const float*)d_in[17];
    float* out = (float*)d_out;

    unsigned char* base = (unsigned char*)d_ws;
    size_t off = 0;
    auto take = [&](size_t bytes) -> void* {
        void* p = base + off;
        off += (bytes + 255) & ~(size_t)255;
        return p;
    };
    u16*   yA     = (u16*)take((size_t)33792 * 512 * 2);
    u16*   yB     = (u16*)take((size_t)33792 * 512 * 2);
    float* xb     = (float*)take((size_t)512 * 2640 * 4);
    u16*   xbf    = (u16*)take((size_t)512 * 4224 * 2);
    float* dct20  = (float*)take(2800);
    float* dctout = (float*)take((size_t)512 * 1320 * 4);
    u16*   key1   = (u16*)take((size_t)512 * 20 * 512 * 2);
    u16*   q1     = (u16*)take((size_t)512 * 5 * 512 * 2);
    float* keyT   = (float*)take((size_t)8192 * 512 * 4);
    float* queryT = (float*)take((size_t)512 * 512 * 4);
    float* attw   = (float*)take((size_t)512 * 16 * 4);
    u16*   WtGcb  = (u16*)take((size_t)4 * 512 * 512 * 2);
    u16*   WtGc1  = (u16*)take((size_t)512 * 64 * 2);
    u16*   WtGc7  = (u16*)take((size_t)128 * 512 * 2);
    u16*   WtW1k  = (u16*)take((size_t)512 * 416 * 2);
    u16*   WtW1q  = (u16*)take((size_t)512 * 416 * 2);
    u16*   WtW2k  = (u16*)take((size_t)512 * 2560 * 2);
    u16*   WtW2q  = (u16*)take((size_t)512 * 2560 * 2);
    u16*   Abf    = (u16*)take((size_t)6 * 8320 * 2);

    dct_kernel<<<2, 384, 0, stream>>>(dct20);
    cvt_att<<<dim3(33, 6), 256, 0, stream>>>(gc1_att, gcb_att, gc7_att, Abf);
    cvt_gcb<<<dim3(1024, 4), 256, 0, stream>>>(gcb_W, WtGcb);
    cvt_gc1<<<128, 256, 0, stream>>>(gc1_W, WtGc1);
    cvt_gc7<<<256, 256, 0, stream>>>(gc7_W, WtGc7);
    cvt_w1<<<832, 256, 0, stream>>>(Wk1, WtW1k);
    cvt_w1<<<832, 256, 0, stream>>>(Wq1, WtW1q);
    cvt_w2<<<5120, 256, 0, stream>>>(Wk2, WtW2k);
    cvt_w2<<<5120, 256, 0, stream>>>(Wq2, WtW2q);

    // conv stacks (im2col is a strided view -> read inputs directly)
    gemm_uni<2, 0, 20, 25, 0><<<dim3(160, 8), 256, 0, stream>>>(
        src, WtW1k, key1, 10240, 416, 512, 512);
    gemm_uni<2, 0, 5, 10, 40><<<dim3(40, 8), 256, 0, stream>>>(
        src, WtW1q, q1, 2560, 416, 512, 512);
    gemm_uni<1, 1, 16, 20, 0><<<dim3(128, 8), 256, 0, stream>>>(
        key1, WtW2k, keyT, 8192, 2560, 512, 512);
    gemm_uni<1, 1, 1, 5, 0><<<dim3(8, 8), 256, 0, stream>>>(
        q1, WtW2q, queryT, 512, 2560, 512, 512);
    att_kernel<<<BSZ, 256, 0, stream>>>(queryT, keyT, attw);
    xbuild<<<BSZ, 256, 0, stream>>>(src, attw, dct20, xb, xbf);

    // gc1: yA = tanh(bn(A1 @ (x @ W1) + b))
    gc_fused<2><<<dim3(512, 4), 256, 0, stream>>>(
        xbf, WtGc1, Abf, yA, 64, gc1_b, bn1_g, bn1_b, nullptr, nullptr);

    // stages
    for (int st = 0; st < 2; ++st) {
        const u16* W0 = WtGcb + (size_t)(st * 2 + 0) * 262144;
        const u16* W1 = WtGcb + (size_t)(st * 2 + 1) * 262144;
        const u16* A0 = Abf + (size_t)(1 + st * 2) * 8320;
        const u16* A1 = Abf + (size_t)(2 + st * 2) * 8320;
        const float* b0  = gcb_b + (size_t)(st * 2 + 0) * 512;
        const float* b1  = gcb_b + (size_t)(st * 2 + 1) * 512;
        const float* g0  = gcb_g + (size_t)(st * 2 + 0) * 33792;
        const float* g1  = gcb_g + (size_t)(st * 2 + 1) * 33792;
        const float* be0 = gcb_be + (size_t)(st * 2 + 0) * 33792;
        const float* be1 = gcb_be + (size_t)(st * 2 + 1) * 33792;
        gc_fused<2><<<dim3(512, 4), 256, 0, stream>>>(
            yA, W0, A0, yB, 512, b0, g0, be0, nullptr, nullptr);
        gc_fused<3><<<dim3(512, 4), 256, 0, stream>>>(
            yB, W1, A1, yA, 512, b1, g1, be1, yA, nullptr);
    }

    // gc7: dctout = A7 @ (y @ W7) + b7 + x  (first 20 cols)
    gc_fused<4><<<dim3(512, 1), 256, 0, stream>>>(
        yA, WtGc7, Abf + (size_t)5 * 8320, dctout, 512, gc7_b, nullptr, nullptr, nullptr, xb);
    final_out<<<BSZ, 256, 0, stream>>>(dctout, dct20, out);
}